// Round 3
// baseline (469.828 us; speedup 1.0000x reference)
//
#include <hip/hip_runtime.h>
#include <cfloat>

// Problem constants (fixed by the reference):
//   inputs  [8,2048,1024] fp32 -> flat [N=16384, H=4, dh=256]
//   codebook[H=4, K=1024, dh=256] fp32
//   out[0] = loss, out[1..] = quantized (16777216 floats)
#define NH    4
#define NK    1024
#define DHD   256
#define NTOK  16384
#define ROWS  (NH * DHD)   // 1024 floats per token row

typedef __attribute__((ext_vector_type(8))) short bf16x8;
typedef __attribute__((ext_vector_type(4))) float f32x4;

// ---------------------------------------------------------------------------
// Workspace layout (bytes). Fast path needs ~4.2 MB; else fp32 fallback.
// ---------------------------------------------------------------------------
#define WS_CSQ  ((size_t)0)
#define WS_BH   ((size_t)16384)                    // cb hi: 4*8*4*1024*16 = 2 MB
#define WS_BL   (WS_BH + (size_t)2097152)          // cb lo: 2 MB
#define WS_NEED (WS_BL + (size_t)2097152)

// ---------------------------------------------------------------------------
// bf16 split helpers (round-to-nearest-even)
// ---------------------------------------------------------------------------
__device__ __forceinline__ unsigned short f32_to_bf16_rn(float f) {
    unsigned u = __float_as_uint(f);
    u += 0x7FFFu + ((u >> 16) & 1u);
    return (unsigned short)(u >> 16);
}
__device__ __forceinline__ float bf16_as_f32(unsigned short h) {
    return __uint_as_float(((unsigned)h) << 16);
}

// direct global->LDS DMA, 16B per lane, dest = wave-uniform base + lane*16
__device__ __forceinline__ void gload_lds16(const uint4* g, uint4* l) {
    __builtin_amdgcn_global_load_lds(
        (const __attribute__((address_space(1))) void*)g,
        (__attribute__((address_space(3))) void*)l, 16, 0, 0);
}

// ---------------------------------------------------------------------------
// Kernel 0: per-code squared norms csq[h*NK + k] = sum_d cb[h][k][d]^2 (fp32)
// ---------------------------------------------------------------------------
__global__ __launch_bounds__(64) void csq_kernel(const float* __restrict__ cb,
                                                 float* __restrict__ csq) {
    const int code = blockIdx.x;                 // 0 .. NH*NK-1
    const int lane = threadIdx.x;
    const float4 v = *(const float4*)(cb + (size_t)code * DHD + lane * 4);
    float s = v.x * v.x + v.y * v.y + v.z * v.z + v.w * v.w;
#pragma unroll
    for (int off = 32; off > 0; off >>= 1) s += __shfl_down(s, off, 64);
    if (lane == 0) csq[code] = s;
}

// ---------------------------------------------------------------------------
// cvt_cb: codebook fp32 -> hi/lo bf16, swizzled [h][dc][kk][code] 16B units
// Block 256 threads = 8 codes.
// ---------------------------------------------------------------------------
__global__ __launch_bounds__(256) void cvt_cb_kernel(const float* __restrict__ cb,
                                                     uint4* __restrict__ bch,
                                                     uint4* __restrict__ bcl) {
    const int g = blockIdx.x * 8 + (threadIdx.x >> 5);   // 0..4095
    const int o = threadIdx.x & 31;                      // dh-octet
    const float* src = cb + (size_t)g * DHD + o * 8;
    unsigned wh[4], wl[4];
#pragma unroll
    for (int i = 0; i < 4; ++i) {
        const float f0 = src[2 * i], f1 = src[2 * i + 1];
        const unsigned short h0 = f32_to_bf16_rn(f0);
        const unsigned short h1 = f32_to_bf16_rn(f1);
        const unsigned short l0 = f32_to_bf16_rn(f0 - bf16_as_f32(h0));
        const unsigned short l1 = f32_to_bf16_rn(f1 - bf16_as_f32(h1));
        wh[i] = (unsigned)h0 | ((unsigned)h1 << 16);
        wl[i] = (unsigned)l0 | ((unsigned)l1 << 16);
    }
    const int hh = g >> 10, c = g & 1023, dc = o >> 2, kk = o & 3;
    const size_t unit = (size_t)((hh * 8 + dc) * 4 + kk) * NK + c;
    bch[unit] = make_uint4(wh[0], wh[1], wh[2], wh[3]);
    bcl[unit] = make_uint4(wl[0], wl[1], wl[2], wl[3]);
}

// first-index "less" for (value, index) pairs
__device__ __forceinline__ bool lt_vi(float v, int i, float w, int j) {
    return (v < w) || (v == w && i < j);
}

// ---------------------------------------------------------------------------
// Bit-exact replica of numpy's pairwise sum of squares for n=256 (VERIFIED R5)
// (retained for the fp32 fallback kernel)
// ---------------------------------------------------------------------------
__device__ __forceinline__ float np_sq_pairwise256(const float* __restrict__ a) {
#pragma clang fp contract(off)
    float tot = 0.f;
#pragma unroll
    for (int blk = 0; blk < 2; ++blk) {
        const float* p = a + blk * 128;
        float r0 = p[0] * p[0], r1 = p[1] * p[1], r2 = p[2] * p[2], r3 = p[3] * p[3];
        float r4 = p[4] * p[4], r5 = p[5] * p[5], r6 = p[6] * p[6], r7 = p[7] * p[7];
#pragma clang loop unroll_count(2)
        for (int i = 8; i < 128; i += 8) {
            r0 = r0 + p[i + 0] * p[i + 0];
            r1 = r1 + p[i + 1] * p[i + 1];
            r2 = r2 + p[i + 2] * p[i + 2];
            r3 = r3 + p[i + 3] * p[i + 3];
            r4 = r4 + p[i + 4] * p[i + 4];
            r5 = r5 + p[i + 5] * p[i + 5];
            r6 = r6 + p[i + 6] * p[i + 6];
            r7 = r7 + p[i + 7] * p[i + 7];
        }
        const float res = ((r0 + r1) + (r2 + r3)) + ((r4 + r5) + (r6 + r7));
        tot = (blk == 0) ? res : (tot + res);
    }
    return tot;
}

// Bit-exact replica of np.einsum's sequential fp32 mul+add loop (VERIFIED R5).
__device__ __forceinline__ float np_dot_seq256(const float* __restrict__ a,
                                               const float* __restrict__ b) {
#pragma clang fp contract(off)
    float s = 0.f;
#pragma clang loop unroll_count(4)
    for (int i = 0; i < 256; ++i) s = s + a[i] * b[i];
    return s;
}

// ---------------------------------------------------------------------------
// Single-pass refinement with SMALL live set (R2's 64-float window spilled to
// scratch: WRITE_SIZE +104MB). 8-float window: 2 float4 loads per array per
// step, named 8-wide accumulators, all indices compile-time.
// Bit-exact vs np_sq_pairwise256 / np_dot_seq256:
//   pairwise-sq: acc j visits p[8g+j] ascending g (init at g=0)  [per 128-blk]
//   dot:         s visits i = blk*128 + g*8 + j strictly ascending
// Interleaving sq/dot updates touches different accumulators -> no fp effect.
// ---------------------------------------------------------------------------
__device__ __forceinline__ void refine_exact(const float* __restrict__ xr,
                                             const float* __restrict__ cr,
                                             float& Xo, float& Co, float& Do) {
#pragma clang fp contract(off)
    float s = 0.f;
    float X = 0.f, C = 0.f;
#pragma unroll
    for (int blk = 0; blk < 2; ++blk) {
        const float4* xq = (const float4*)(xr + blk * 128);
        const float4* cq = (const float4*)(cr + blk * 128);
        float xa[8], ca[8];
#pragma unroll
        for (int g = 0; g < 16; ++g) {
            const float4 a0 = xq[2 * g], a1 = xq[2 * g + 1];
            const float4 b0 = cq[2 * g], b1 = cq[2 * g + 1];
            const float xf[8] = {a0.x, a0.y, a0.z, a0.w, a1.x, a1.y, a1.z, a1.w};
            const float cf[8] = {b0.x, b0.y, b0.z, b0.w, b1.x, b1.y, b1.z, b1.w};
            if (g == 0) {
#pragma unroll
                for (int j = 0; j < 8; ++j) { xa[j] = xf[j] * xf[j]; ca[j] = cf[j] * cf[j]; }
            } else {
#pragma unroll
                for (int j = 0; j < 8; ++j) {
                    xa[j] = xa[j] + xf[j] * xf[j];
                    ca[j] = ca[j] + cf[j] * cf[j];
                }
            }
#pragma unroll
            for (int j = 0; j < 8; ++j) s = s + xf[j] * cf[j];
        }
        const float xres = ((xa[0] + xa[1]) + (xa[2] + xa[3])) + ((xa[4] + xa[5]) + (xa[6] + xa[7]));
        const float cres = ((ca[0] + ca[1]) + (ca[2] + ca[3])) + ((ca[4] + ca[5]) + (ca[6] + ca[7]));
        X = (blk == 0) ? xres : (X + xres);
        C = (blk == 0) ? cres : (C + cres);
    }
    Xo = X; Co = C; Do = s;
}

// ===========================================================================
// FAST PATH: split-bf16 MFMA kernel, occupancy-first restructure.
// 1024 blocks (XCD-swizzled) x 256 thr / 4 waves; block = 64 tokens
// (wave w: tokens w*16..w*16+15, ONE 16-row MFMA tile -> A-frags 64 VGPR).
// Codes in KT=16 tiles, double-buffered LDS (36.8 KB total -> 4 blocks/CU,
// 16 waves/CU). STAGE(next) issued before compute(cur), 1 barrier/tile.
// dot = hi*hi + hi*lo + lo*hi via mfma_f32_16x16x32_bf16, even/odd-dc
// accumulator split (screen-only; refinement recomputes exactly).
// Layouts (doc-verified): A-frag A[m=lane&15][k=(lane>>4)*8+j];
// B-frag (B^T input [code][dh]): B[n=lane&15][k=(lane>>4)*8+j];
// C/D: col(n)=lane&15, row(m)=(lane>>4)*4+reg.
// ===========================================================================
#define BT 64          // tokens per block
#define KT 16          // codes per tile
#define NT (NK / KT)   // 64 tiles

// Per-wave stage of one 16-code tile (hi+lo) into buffer BUF.
// 512 units/array per tile; 8 wave-loads/array; wave wv does q = wv*2+p.
// Lane l -> row q*4+(l>>4), col l&15; dest unit q*64+l (linear match).
#define STAGE_TILE(BUF, K0)                                                    \
    {                                                                          \
        _Pragma("unroll")                                                      \
        for (int p_ = 0; p_ < 2; ++p_) {                                       \
            const int q_   = wv * 2 + p_;                                      \
            const int row_ = q_ * 4 + (lane >> 4);                             \
            const size_t w_ = (size_t)(h * 32 + row_) * NK + (K0) + (lane & 15); \
            gload_lds16(&bch[w_], &BsH[BUF][q_ * 64]);                         \
            gload_lds16(&bcl[w_], &BsL[BUF][q_ * 64]);                         \
        }                                                                      \
    }

__global__ __launch_bounds__(256, 4) void vq_mfma(const float* __restrict__ x,
                                                  const float* __restrict__ cb,
                                                  const float* __restrict__ csq,
                                                  const uint4* __restrict__ bch,
                                                  const uint4* __restrict__ bcl,
                                                  float* __restrict__ out) {
    __shared__ uint4 BsH[2][512];    // 2 buf x (16 codes x 256 dh hi) [dcKK(32)][code(16)]
    __shared__ uint4 BsL[2][512];    // lo
    __shared__ float Cs[NK];         // per-head code norms, loaded once
    __shared__ int   Cand[BT][2];
    __shared__ int   SIdx[BT];
    __shared__ float WSum[4];

    const int tid  = threadIdx.x;
    // Bijective XCD swizzle: hardware round-robins consecutive block ids over
    // 8 XCDs; remap so each XCD owns 128 consecutive blocks = half a head
    // (its 2 MB B working set stays L2-local).
    const int wg   = blockIdx.x + gridDim.x * blockIdx.y;   // 0..1023
    const int sw   = (wg & 7) * 128 + (wg >> 3);            // bijective on 1024
    const int h    = sw >> 8;
    const int t0   = (sw & 255) * BT;
    const int wv   = tid >> 6;
    const int lane = tid & 63;
    const int kk   = lane >> 4;    // 0..3 (k-octet)
    const int ln   = lane & 15;

    const float* xh  = x  + (size_t)t0 * ROWS + h * DHD;
    const float* cbh = cb + (size_t)h * NK * DHD;

    // Issue first B-tile DMA immediately; completes under Cs + A-build.
    STAGE_TILE(0, 0)

    // Code norms: whole head once.
#pragma unroll
    for (int i = tid; i < NK; i += 256) Cs[i] = csq[h * NK + i];

    // A fragments: token-stationary, whole dh in registers (hi+lo, 64 VGPR),
    // converted in-registers from fp32 x (bit-exact split).
    bf16x8 aH[8], aL[8];
    {
        const int tokb = t0 + wv * 16 + ln;
        const float* xa = x + (size_t)tokb * ROWS + h * DHD + kk * 8;
#pragma unroll
        for (int dc = 0; dc < 8; ++dc) {
            const float* p = xa + dc * 32;
            const float4 f0 = *(const float4*)p;
            const float4 f1 = *(const float4*)(p + 4);
            const float f[8] = {f0.x, f0.y, f0.z, f0.w, f1.x, f1.y, f1.z, f1.w};
            bf16x8 hv, lv;
#pragma unroll
            for (int j = 0; j < 8; ++j) {
                const unsigned short hb = f32_to_bf16_rn(f[j]);
                hv[j] = (short)hb;
                lv[j] = (short)f32_to_bf16_rn(f[j] - bf16_as_f32(hb));
            }
            aH[dc] = hv;
            aL[dc] = lv;
        }
    }

    float b1[4], b2[4];
    int   i1[4], i2[4];
#pragma unroll
    for (int s = 0; s < 4; ++s) { b1[s] = FLT_MAX; b2[s] = FLT_MAX; i1[s] = 0; i2[s] = 0; }

    __syncthreads();   // drains vmcnt(0): tile 0 staged, Cs ready
    int cur = 0;

    for (int t = 0; t < NT; ++t) {
        const int k0 = t * KT;
        // Prefetch next tile into the other buffer (hides under compute).
        if (t + 1 < NT) STAGE_TILE(cur ^ 1, k0 + KT)

        // Even/odd-dc accumulator split: 2 independent MFMA chains per wave
        // (screen only; summed before use -> no effect on refinement).
        f32x4 acc0 = (f32x4){0.f, 0.f, 0.f, 0.f};
        f32x4 acc1 = (f32x4){0.f, 0.f, 0.f, 0.f};
#pragma unroll
        for (int dc = 0; dc < 8; dc += 2) {
            const int bu0 = ((dc + 0) * 4 + kk) * 16 + ln;
            const int bu1 = ((dc + 1) * 4 + kk) * 16 + ln;
            const bf16x8 bH0 = *(const bf16x8*)&BsH[cur][bu0];
            const bf16x8 bL0 = *(const bf16x8*)&BsL[cur][bu0];
            const bf16x8 bH1 = *(const bf16x8*)&BsH[cur][bu1];
            const bf16x8 bL1 = *(const bf16x8*)&BsL[cur][bu1];
            acc0 = __builtin_amdgcn_mfma_f32_16x16x32_bf16(aH[dc + 0], bH0, acc0, 0, 0, 0);
            acc1 = __builtin_amdgcn_mfma_f32_16x16x32_bf16(aH[dc + 1], bH1, acc1, 0, 0, 0);
            acc0 = __builtin_amdgcn_mfma_f32_16x16x32_bf16(aH[dc + 0], bL0, acc0, 0, 0, 0);
            acc1 = __builtin_amdgcn_mfma_f32_16x16x32_bf16(aH[dc + 1], bL1, acc1, 0, 0, 0);
            acc0 = __builtin_amdgcn_mfma_f32_16x16x32_bf16(aL[dc + 0], bH0, acc0, 0, 0, 0);
            acc1 = __builtin_amdgcn_mfma_f32_16x16x32_bf16(aL[dc + 1], bH1, acc1, 0, 0, 0);
        }

        // distances (x_sq dropped: per-token constant) + running top-2
        const float cs   = Cs[k0 + ln];
        const int   codg = k0 + ln;
#pragma unroll
        for (int r = 0; r < 4; ++r) {
            const float dist = cs - 2.f * (acc0[r] + acc1[r]);
            if (dist < b1[r]) { b2[r] = b1[r]; i2[r] = i1[r]; b1[r] = dist; i1[r] = codg; }
            else if (dist < b2[r]) { b2[r] = dist; i2[r] = codg; }
        }

        // Barrier: drains next-tile DMA (vmcnt) + all waves done reading cur.
        __syncthreads();
        cur ^= 1;
    }

    // Merge top-2 across the 16 lanes sharing each token (xor bits 0..3;
    // token row m = kk*4+r lives at lanes {kk*16 + ln : ln=0..15}).
#pragma unroll
    for (int s = 0; s < 4; ++s) {
        float v1 = b1[s], v2 = b2[s];
        int   j1 = i1[s], j2 = i2[s];
#pragma unroll
        for (int m = 1; m <= 8; m <<= 1) {
            const float o1 = __shfl_xor(v1, m, 64);
            const int   oj1 = __shfl_xor(j1, m, 64);
            const float o2 = __shfl_xor(v2, m, 64);
            const int   oj2 = __shfl_xor(j2, m, 64);
            if (lt_vi(o1, oj1, v1, j1)) {
                if (lt_vi(v1, j1, o2, oj2)) { v2 = v1; j2 = j1; }
                else                        { v2 = o2; j2 = oj2; }
                v1 = o1; j1 = oj1;
            } else if (lt_vi(o1, oj1, v2, j2)) {
                v2 = o1; j2 = oj1;
            }
        }
        if (ln == 0) {
            const int tl = wv * 16 + kk * 4 + s;
            Cand[tl][0] = j1;
            Cand[tl][1] = j2;
        }
    }
    __syncthreads();

    // Refinement: bit-exact numpy emulation on 2 candidates (small-live-set
    // single-pass; semantics VERIFIED R5/R6, load order has no fp effect).
    if (tid < 2 * BT) {
        const int token = tid >> 1;          // 0..63
        const int cand  = tid & 1;
        const int code  = Cand[token][cand];
        const float* xr = xh + (size_t)token * ROWS;
        const float* cr = cbh + (size_t)code * DHD;
        float X, C, D;
        refine_exact(xr, cr, X, C, D);
        float d;
        {
#pragma clang fp contract(off)
            const float t = X + C;
            d = t - 2.0f * D;
        }
        const float od = __shfl_xor(d, 1, 64);
        if (cand == 0) {
            const int jA = code;
            const int jB = Cand[token][1];
            const bool pickB = (od < d) || (od == d && jB < jA);
            SIdx[token] = pickB ? jB : jA;
        }
    }
    __syncthreads();

    // Epilogue: gather codebook rows -> out (float4), accumulate (q-x)^2.
    float lacc = 0.f;
    for (int t = wv; t < BT; t += 4) {
        const float4 q4 = *(const float4*)(cbh + (size_t)SIdx[t] * DHD + (lane << 2));
        const float4 x4 = *(const float4*)(xh + (size_t)t * ROWS + (lane << 2));
        const float dx = q4.x - x4.x, dy = q4.y - x4.y;
        const float dz = q4.z - x4.z, dw = q4.w - x4.w;
        lacc += dx * dx + dy * dy + dz * dz + dw * dw;
        *(float4*)(out + 1 + (size_t)(t0 + t) * ROWS + h * DHD + (lane << 2)) = q4;
    }
#pragma unroll
    for (int off = 32; off > 0; off >>= 1) lacc += __shfl_down(lacc, off, 64);
    if (lane == 0) WSum[wv] = lacc;
    __syncthreads();
    if (tid == 0) {
        const float s = WSum[0] + WSum[1] + WSum[2] + WSum[3];
        atomicAdd(out, s * (0.25f / 16777216.f));  // 0.25 * mean
    }
}

// ===========================================================================
// FALLBACK (ws too small): R6 fp32 kernel — verified passing at 558 us.
// ===========================================================================
#define TN 128
#define TK 128
#define KC 16
#define APAD 4
#define BPAD 4

__global__ __launch_bounds__(256, 2) void vq_main_fp32(const float* __restrict__ x,
                                                       const float* __restrict__ cb,
                                                       const float* __restrict__ csq,
                                                       float* __restrict__ out) {
    __shared__ float As[KC][TN + APAD];
    __shared__ float Bs[KC][TK + BPAD];
    __shared__ float Cs[TK];
    __shared__ int   Cand[TN][2];
    __shared__ int   SIdx[TN];
    __shared__ float WSum[4];

    const int tid = threadIdx.x;
    const int h   = blockIdx.y;
    const int t0  = blockIdx.x * TN;
    const int ty  = tid >> 4;
    const int tx  = tid & 15;

    const float* xh  = x  + (size_t)t0 * ROWS + h * DHD;
    const float* cbh = cb + (size_t)h * NK * DHD;

    const int sr = tid >> 1;
    const int sd = (tid & 1) << 3;

    float b1[8], b2[8];
    int   i1[8], i2[8];
#pragma unroll
    for (int r = 0; r < 8; ++r) { b1[r] = FLT_MAX; b2[r] = FLT_MAX; i1[r] = 0; i2[r] = 0; }

    for (int k0 = 0; k0 < NK; k0 += TK) {
        __syncthreads();
        if (tid < TK) Cs[tid] = csq[h * NK + k0 + tid];

        float acc[8][8];
#pragma unroll
        for (int r = 0; r < 8; ++r)
#pragma unroll
            for (int c = 0; c < 8; ++c) acc[r][c] = 0.f;

        for (int d0 = 0; d0 < DHD; d0 += KC) {
            __syncthreads();
            {
                const float* ap = xh + (size_t)sr * ROWS + d0 + sd;
                const float4 a0 = *(const float4*)ap;
                const float4 a1 = *(const float4*)(ap + 4);
                As[sd + 0][sr] = a0.x; As[sd + 1][sr] = a0.y;
                As[sd + 2][sr] = a0.z; As[sd + 3][sr] = a0.w;
                As[sd + 4][sr] = a1.x; As[sd + 5][sr] = a1.y;
                As[sd + 6][sr] = a1.z; As[sd + 7][sr] = a1.w;
            }
            {
                const float* bp = cbh + (size_t)(k0 + sr) * DHD + d0 + sd;
                const float4 b0v = *(const float4*)bp;
                const float4 b1v = *(const float4*)(bp + 4);
                Bs[sd + 0][sr] = b0v.x; Bs[sd + 1][sr] = b0v.y;
                Bs[sd + 2][sr] = b0v.z; Bs[sd + 3][sr] = b0v.w;
                Bs[sd + 4][sr] = b1v.x; Bs[sd + 5][sr] = b1v.y;
                Bs[sd + 6][sr] = b1v.z; Bs[sd + 7][sr] = b1v.w;
            }
            __syncthreads();
#pragma unroll 4
            for (int kc = 0; kc < KC; ++kc) {
                const float4 a0 = *(const float4*)&As[kc][ty << 3];
                const float4 a1 = *(const float4*)&As[kc][(ty << 3) + 4];
                const float4 p0 = *(const float4*)&Bs[kc][tx << 2];
                const float4 p1 = *(const float4*)&Bs[kc][64 + (tx << 2)];
                const float aa[8] = {a0.x, a0.y, a0.z, a0.w, a1.x, a1.y, a1.z, a1.w};
                const float bb[8] = {p0.x, p0.y, p0.z, p0.w, p1.x, p1.y, p1.z, p1.w};
#pragma unroll
                for (int r = 0; r < 8; ++r)
#pragma unroll
                    for (int c = 0; c < 8; ++c)
                        acc[r][c] = fmaf(aa[r], bb[c], acc[r][c]);
            }
        }
#pragma unroll
        for (int r = 0; r < 8; ++r) {
#pragma unroll
            for (int c = 0; c < 8; ++c) {
                const int cc = (c < 4) ? ((tx << 2) + c) : (64 + (tx << 2) + c - 4);
                const float dist = Cs[cc] - 2.f * acc[r][c];
                const int   idx  = k0 + cc;
                if (dist < b1[r]) { b2[r] = b1[r]; i2[r] = i1[r]; b1[r] = dist; i1[r] = idx; }
                else if (dist < b2[r]) { b2[r] = dist; i2[r] = idx; }
            }
        }
    }

#pragma unroll
    for (int r = 0; r < 8; ++r) {
        float v1 = b1[r], v2 = b2[r];
        int   j1 = i1[r], j2 = i2[r];
#pragma unroll
        for (int m = 1; m <= 8; m <<= 1) {
            const float o1 = __shfl_xor(v1, m, 64);
            const int   oj1 = __shfl_xor(j1, m, 64);
            const float o2 = __shfl_xor(v2, m, 64);
            const int   oj2 = __shfl_xor(j2, m, 64);
            if (lt_vi(o1, oj1, v1, j1)) {
                if (lt_vi(v1, j1, o2, oj2)) { v2 = v1; j2 = j1; }
                else                        { v2 = o2; j2 = oj2; }
                v1 = o1; j1 = oj1;
            } else if (lt_vi(o1, oj1, v2, j2)) {
                v2 = o1; j2 = oj1;
            }
        }
        b1[r] = v1; i1[r] = j1; b2[r] = v2; i2[r] = j2;
    }
    if (tx == 0) {
#pragma unroll
        for (int r = 0; r < 8; ++r) {
            Cand[(ty << 3) + r][0] = i1[r];
            Cand[(ty << 3) + r][1] = i2[r];
        }
    }
    __syncthreads();

    {
        const int token = tid >> 1;
        const int cand  = tid & 1;
        const int code  = Cand[token][cand];
        const float* xr = xh + (size_t)token * ROWS;
        const float* cr = cbh + (size_t)code * DHD;
        const float X = np_sq_pairwise256(xr);
        const float C = np_sq_pairwise256(cr);
        const float D = np_dot_seq256(xr, cr);
        float d;
        {
#pragma clang fp contract(off)
            const float t = X + C;
            d = t - 2.0f * D;
        }
        const float od = __shfl_xor(d, 1, 64);
        if (cand == 0) {
            const int jA = code;
            const int jB = Cand[token][1];
            const bool pickB = (od < d) || (od == d && jB < jA);
            SIdx[token] = pickB ? jB : jA;
        }
    }
    __syncthreads();

    const int wav  = tid >> 6;
    const int lane = tid & 63;
    float lacc = 0.f;
    for (int t = wav; t < TN; t += 4) {
        const float4 q4 = *(const float4*)(cbh + (size_t)SIdx[t] * DHD + (lane << 2));
        const float4 x4 = *(const float4*)(xh + (size_t)t * ROWS + (lane << 2));
        const float dx = q4.x - x4.x, dy = q4.y - x4.y;
        const float dz = q4.z - x4.z, dw = q4.w - x4.w;
        lacc += dx * dx + dy * dy + dz * dz + dw * dw;
        *(float4*)(out + 1 + (size_t)(t0 + t) * ROWS + h * DHD + (lane << 2)) = q4;
    }
#pragma unroll
    for (int off = 32; off > 0; off >>= 1) lacc += __shfl_down(lacc, off, 64);
    if (lane == 0) WSum[wav] = lacc;
    __syncthreads();
    if (tid == 0) {
        const float s = WSum[0] + WSum[1] + WSum[2] + WSum[3];
        atomicAdd(out, s * (0.25f / 16777216.f));
    }
}

extern "C" void kernel_launch(void* const* d_in, const int* in_sizes, int n_in,
                              void* d_out, int out_size, void* d_ws, size_t ws_size,
                              hipStream_t stream) {
    const float* x   = (const float*)d_in[0];   // inputs  [16777216]
    const float* cb  = (const float*)d_in[1];   // codebook [1048576]
    float*       out = (float*)d_out;           // [1 + 16777216]
    char*        ws  = (char*)d_ws;
    float*       csq = (float*)(ws + WS_CSQ);

    hipMemsetAsync(d_out, 0, sizeof(float), stream);
    csq_kernel<<<NH * NK, 64, 0, stream>>>(cb, csq);

    if (ws_size >= WS_NEED) {
        uint4* bch = (uint4*)(ws + WS_BH);
        uint4* bcl = (uint4*)(ws + WS_BL);
        cvt_cb_kernel<<<NH * NK / 8, 256, 0, stream>>>(cb, bch, bcl);
        dim3 grid(NTOK / BT, NH);
        vq_mfma<<<grid, 256, 0, stream>>>(x, cb, csq, bch, bcl, out);
    } else {
        dim3 grid(NTOK / TN, NH);
        vq_main_fp32<<<grid, 256, 0, stream>>>(x, cb, csq, out);
    }
}

// Round 4
// 389.085 us; speedup vs baseline: 1.2075x; 1.2075x over previous
//
#include <hip/hip_runtime.h>
#include <cfloat>

// Problem constants (fixed by the reference):
//   inputs  [8,2048,1024] fp32 -> flat [N=16384, H=4, dh=256]
//   codebook[H=4, K=1024, dh=256] fp32
//   out[0] = loss, out[1..] = quantized (16777216 floats)
#define NH    4
#define NK    1024
#define DHD   256
#define NTOK  16384
#define ROWS  (NH * DHD)   // 1024 floats per token row

typedef __attribute__((ext_vector_type(8))) short bf16x8;
typedef __attribute__((ext_vector_type(4))) float f32x4;

// ---------------------------------------------------------------------------
// Workspace layout (bytes). Fast path needs ~4.2 MB; else fp32 fallback.
// ---------------------------------------------------------------------------
#define WS_CSQ  ((size_t)0)
#define WS_BH   ((size_t)16384)                    // cb hi: 4*8*4*1024*16 = 2 MB
#define WS_BL   (WS_BH + (size_t)2097152)          // cb lo: 2 MB
#define WS_NEED (WS_BL + (size_t)2097152)

// ---------------------------------------------------------------------------
// bf16 split helpers (round-to-nearest-even)
// ---------------------------------------------------------------------------
__device__ __forceinline__ unsigned short f32_to_bf16_rn(float f) {
    unsigned u = __float_as_uint(f);
    u += 0x7FFFu + ((u >> 16) & 1u);
    return (unsigned short)(u >> 16);
}
__device__ __forceinline__ float bf16_as_f32(unsigned short h) {
    return __uint_as_float(((unsigned)h) << 16);
}

// direct global->LDS DMA, 16B per lane, dest = wave-uniform base + lane*16
__device__ __forceinline__ void gload_lds16(const uint4* g, uint4* l) {
    __builtin_amdgcn_global_load_lds(
        (const __attribute__((address_space(1))) void*)g,
        (__attribute__((address_space(3))) void*)l, 16, 0, 0);
}

// ---------------------------------------------------------------------------
// Kernel 0: per-code squared norms csq[h*NK + k] = sum_d cb[h][k][d]^2 (fp32)
// ---------------------------------------------------------------------------
__global__ __launch_bounds__(64) void csq_kernel(const float* __restrict__ cb,
                                                 float* __restrict__ csq) {
    const int code = blockIdx.x;                 // 0 .. NH*NK-1
    const int lane = threadIdx.x;
    const float4 v = *(const float4*)(cb + (size_t)code * DHD + lane * 4);
    float s = v.x * v.x + v.y * v.y + v.z * v.z + v.w * v.w;
#pragma unroll
    for (int off = 32; off > 0; off >>= 1) s += __shfl_down(s, off, 64);
    if (lane == 0) csq[code] = s;
}

// ---------------------------------------------------------------------------
// cvt_cb: codebook fp32 -> hi/lo bf16, swizzled [h][dc][kk][code] 16B units
// Block 256 threads = 8 codes.
// ---------------------------------------------------------------------------
__global__ __launch_bounds__(256) void cvt_cb_kernel(const float* __restrict__ cb,
                                                     uint4* __restrict__ bch,
                                                     uint4* __restrict__ bcl) {
    const int g = blockIdx.x * 8 + (threadIdx.x >> 5);   // 0..4095
    const int o = threadIdx.x & 31;                      // dh-octet
    const float* src = cb + (size_t)g * DHD + o * 8;
    unsigned wh[4], wl[4];
#pragma unroll
    for (int i = 0; i < 4; ++i) {
        const float f0 = src[2 * i], f1 = src[2 * i + 1];
        const unsigned short h0 = f32_to_bf16_rn(f0);
        const unsigned short h1 = f32_to_bf16_rn(f1);
        const unsigned short l0 = f32_to_bf16_rn(f0 - bf16_as_f32(h0));
        const unsigned short l1 = f32_to_bf16_rn(f1 - bf16_as_f32(h1));
        wh[i] = (unsigned)h0 | ((unsigned)h1 << 16);
        wl[i] = (unsigned)l0 | ((unsigned)l1 << 16);
    }
    const int hh = g >> 10, c = g & 1023, dc = o >> 2, kk = o & 3;
    const size_t unit = (size_t)((hh * 8 + dc) * 4 + kk) * NK + c;
    bch[unit] = make_uint4(wh[0], wh[1], wh[2], wh[3]);
    bcl[unit] = make_uint4(wl[0], wl[1], wl[2], wl[3]);
}

// first-index "less" for (value, index) pairs
__device__ __forceinline__ bool lt_vi(float v, int i, float w, int j) {
    return (v < w) || (v == w && i < j);
}

// ---------------------------------------------------------------------------
// Bit-exact replica of numpy's pairwise sum of squares for n=256 (VERIFIED R5)
// (retained for the fp32 fallback kernel)
// ---------------------------------------------------------------------------
__device__ __forceinline__ float np_sq_pairwise256(const float* __restrict__ a) {
#pragma clang fp contract(off)
    float tot = 0.f;
#pragma unroll
    for (int blk = 0; blk < 2; ++blk) {
        const float* p = a + blk * 128;
        float r0 = p[0] * p[0], r1 = p[1] * p[1], r2 = p[2] * p[2], r3 = p[3] * p[3];
        float r4 = p[4] * p[4], r5 = p[5] * p[5], r6 = p[6] * p[6], r7 = p[7] * p[7];
#pragma clang loop unroll_count(2)
        for (int i = 8; i < 128; i += 8) {
            r0 = r0 + p[i + 0] * p[i + 0];
            r1 = r1 + p[i + 1] * p[i + 1];
            r2 = r2 + p[i + 2] * p[i + 2];
            r3 = r3 + p[i + 3] * p[i + 3];
            r4 = r4 + p[i + 4] * p[i + 4];
            r5 = r5 + p[i + 5] * p[i + 5];
            r6 = r6 + p[i + 6] * p[i + 6];
            r7 = r7 + p[i + 7] * p[i + 7];
        }
        const float res = ((r0 + r1) + (r2 + r3)) + ((r4 + r5) + (r6 + r7));
        tot = (blk == 0) ? res : (tot + res);
    }
    return tot;
}

// Bit-exact replica of np.einsum's sequential fp32 mul+add loop (VERIFIED R5).
__device__ __forceinline__ float np_dot_seq256(const float* __restrict__ a,
                                               const float* __restrict__ b) {
#pragma clang fp contract(off)
    float s = 0.f;
#pragma clang loop unroll_count(4)
    for (int i = 0; i < 256; ++i) s = s + a[i] * b[i];
    return s;
}

// ---------------------------------------------------------------------------
// Single-pass refinement with SMALL live set (R2's 64-float window spilled;
// this 8-float window did not spill by itself). 2 float4 loads per array per
// step, named 8-wide accumulators, all indices compile-time.
// Bit-exact vs np_sq_pairwise256 / np_dot_seq256:
//   pairwise-sq: acc j visits p[8g+j] ascending g (init at g=0)  [per 128-blk]
//   dot:         s visits i = blk*128 + g*8 + j strictly ascending
// Interleaving sq/dot updates touches different accumulators -> no fp effect.
// ---------------------------------------------------------------------------
__device__ __forceinline__ void refine_exact(const float* __restrict__ xr,
                                             const float* __restrict__ cr,
                                             float& Xo, float& Co, float& Do) {
#pragma clang fp contract(off)
    float s = 0.f;
    float X = 0.f, C = 0.f;
#pragma unroll
    for (int blk = 0; blk < 2; ++blk) {
        const float4* xq = (const float4*)(xr + blk * 128);
        const float4* cq = (const float4*)(cr + blk * 128);
        float xa[8], ca[8];
#pragma unroll
        for (int g = 0; g < 16; ++g) {
            const float4 a0 = xq[2 * g], a1 = xq[2 * g + 1];
            const float4 b0 = cq[2 * g], b1 = cq[2 * g + 1];
            const float xf[8] = {a0.x, a0.y, a0.z, a0.w, a1.x, a1.y, a1.z, a1.w};
            const float cf[8] = {b0.x, b0.y, b0.z, b0.w, b1.x, b1.y, b1.z, b1.w};
            if (g == 0) {
#pragma unroll
                for (int j = 0; j < 8; ++j) { xa[j] = xf[j] * xf[j]; ca[j] = cf[j] * cf[j]; }
            } else {
#pragma unroll
                for (int j = 0; j < 8; ++j) {
                    xa[j] = xa[j] + xf[j] * xf[j];
                    ca[j] = ca[j] + cf[j] * cf[j];
                }
            }
#pragma unroll
            for (int j = 0; j < 8; ++j) s = s + xf[j] * cf[j];
        }
        const float xres = ((xa[0] + xa[1]) + (xa[2] + xa[3])) + ((xa[4] + xa[5]) + (xa[6] + xa[7]));
        const float cres = ((ca[0] + ca[1]) + (ca[2] + ca[3])) + ((ca[4] + ca[5]) + (ca[6] + ca[7]));
        X = (blk == 0) ? xres : (X + xres);
        C = (blk == 0) ? cres : (C + cres);
    }
    Xo = X; Co = C; Do = s;
}

// ===========================================================================
// FAST PATH: split-bf16 MFMA kernel — R1 structure (the proven 255us body)
// with KT=32 single-buffered B tiles (LDS 37.8KB: occupancy no longer
// LDS-capped), whole-head Cs, XCD swizzle, fast single-pass refinement.
// NO forced occupancy bound: launch_bounds(256,2) is the only configuration
// that never triggered spill (R2/R3 post-mortems).
// Grid 512 blocks x 256 thr / 4 waves; block = 128 tokens; wave w: tokens
// w*32..w*32+31 (2 MFMA row-tiles of 16). Codes in 32-wide tiles (2 col-
// tiles). dot = hi*hi + hi*lo + lo*hi via mfma_f32_16x16x32_bf16.
// Layouts (doc-verified): A-frag A[m=lane&15][k=(lane>>4)*8+j];
// B-frag (B^T input [code][dh]): B[n=lane&15][k=(lane>>4)*8+j];
// C/D: col(n)=lane&15, row(m)=(lane>>4)*4+reg.
// ===========================================================================
#define KT 32          // codes per tile
#define NT (NK / KT)   // 32 tiles

__global__ __launch_bounds__(256, 2) void vq_mfma(const float* __restrict__ x,
                                                  const float* __restrict__ cb,
                                                  const float* __restrict__ csq,
                                                  const uint4* __restrict__ bch,
                                                  const uint4* __restrict__ bcl,
                                                  float* __restrict__ out) {
    __shared__ uint4 BsH[1024];    // 32 codes x 256 dh (hi) as [dcKK(32)][code(32)]
    __shared__ uint4 BsL[1024];    // lo
    __shared__ float Cs[NK];       // per-head code norms, loaded once
    __shared__ int   Cand[128][2];
    __shared__ int   SIdx[128];
    __shared__ float WSum[4];

    const int tid  = threadIdx.x;
    // Bijective XCD swizzle: hardware round-robins consecutive block ids over
    // 8 XCDs; remap so each XCD owns 64 consecutive blocks = half a head
    // (its ~1MB B working set and x rows stay L2-local). 512 = 8*64 exact.
    const int wg   = blockIdx.x + gridDim.x * blockIdx.y;   // 0..511
    const int sw   = (wg & 7) * 64 + (wg >> 3);             // bijective on 512
    const int h    = sw >> 7;
    const int t0   = (sw & 127) * 128;
    const int wv   = tid >> 6;
    const int lane = tid & 63;
    const int kk   = lane >> 4;    // 0..3 (k-octet)
    const int ln   = lane & 15;

    const float* xh  = x  + (size_t)t0 * ROWS + h * DHD;
    const float* cbh = cb + (size_t)h * NK * DHD;

    // Code norms: whole head once.
#pragma unroll
    for (int i = tid; i < NK; i += 256) Cs[i] = csq[h * NK + i];

    // A fragments: token-stationary, whole dh in registers (hi+lo),
    // converted in-registers from fp32 x (bit-exact split).
    bf16x8 aH[2][8], aL[2][8];
    {
        const int tokb = t0 + wv * 32 + ln;
        const float* xa = x + (size_t)tokb * ROWS + h * DHD + kk * 8;
#pragma unroll
        for (int rt = 0; rt < 2; ++rt) {
#pragma unroll
            for (int dc = 0; dc < 8; ++dc) {
                const float* p = xa + (size_t)(rt * 16) * ROWS + dc * 32;
                const float4 f0 = *(const float4*)p;
                const float4 f1 = *(const float4*)(p + 4);
                const float f[8] = {f0.x, f0.y, f0.z, f0.w, f1.x, f1.y, f1.z, f1.w};
                bf16x8 hv, lv;
#pragma unroll
                for (int j = 0; j < 8; ++j) {
                    const unsigned short hb = f32_to_bf16_rn(f[j]);
                    hv[j] = (short)hb;
                    lv[j] = (short)f32_to_bf16_rn(f[j] - bf16_as_f32(hb));
                }
                aH[rt][dc] = hv;
                aL[rt][dc] = lv;
            }
        }
    }

    float b1[8], b2[8];
    int   i1[8], i2[8];
#pragma unroll
    for (int s = 0; s < 8; ++s) { b1[s] = FLT_MAX; b2[s] = FLT_MAX; i1[s] = 0; i2[s] = 0; }

    for (int t = 0; t < NT; ++t) {
        const int k0 = t * KT;
        __syncthreads();  // protect Bs/Cs from previous-iteration readers
        // stage B tile: 1024 hi + 1024 lo units via direct global->LDS DMA.
        // Wave wv, chunk q=wv*4+p: lane l -> row 2q+(l>>5), col l&31;
        // LDS dest unit q*64+l == row*32+col (linear match, wave-uniform base).
#pragma unroll
        for (int p = 0; p < 4; ++p) {
            const int q   = wv * 4 + p;
            const int row = 2 * q + (lane >> 5);
            const size_t w = (size_t)(h * 32 + row) * NK + k0 + (lane & 31);
            gload_lds16(&bch[w], &BsH[q * 64]);
            gload_lds16(&bcl[w], &BsL[q * 64]);
        }
        __syncthreads();  // drains vmcnt(0): DMA'd tile visible

        f32x4 acc[2][2];
#pragma unroll
        for (int rt = 0; rt < 2; ++rt)
#pragma unroll
            for (int ct = 0; ct < 2; ++ct) acc[rt][ct] = (f32x4){0.f, 0.f, 0.f, 0.f};

#pragma unroll
        for (int dc = 0; dc < 8; ++dc) {
#pragma unroll
            for (int ct = 0; ct < 2; ++ct) {
                const int bu = (dc * 4 + kk) * 32 + ct * 16 + ln;
                const bf16x8 bH = *(const bf16x8*)&BsH[bu];
                const bf16x8 bL = *(const bf16x8*)&BsL[bu];
#pragma unroll
                for (int rt = 0; rt < 2; ++rt) {
                    acc[rt][ct] = __builtin_amdgcn_mfma_f32_16x16x32_bf16(aH[rt][dc], bH, acc[rt][ct], 0, 0, 0);
                    acc[rt][ct] = __builtin_amdgcn_mfma_f32_16x16x32_bf16(aH[rt][dc], bL, acc[rt][ct], 0, 0, 0);
                    acc[rt][ct] = __builtin_amdgcn_mfma_f32_16x16x32_bf16(aL[rt][dc], bH, acc[rt][ct], 0, 0, 0);
                }
            }
        }

        // distances (x_sq dropped: per-token constant) + running top-2
#pragma unroll
        for (int rt = 0; rt < 2; ++rt)
#pragma unroll
            for (int ct = 0; ct < 2; ++ct) {
                const float cs   = Cs[k0 + ct * 16 + ln];
                const int   codg = k0 + ct * 16 + ln;
#pragma unroll
                for (int r = 0; r < 4; ++r) {
                    const float dist = cs - 2.f * acc[rt][ct][r];
                    const int   s    = rt * 4 + r;
                    if (dist < b1[s]) { b2[s] = b1[s]; i2[s] = i1[s]; b1[s] = dist; i1[s] = codg; }
                    else if (dist < b2[s]) { b2[s] = dist; i2[s] = codg; }
                }
            }
    }

    // Merge top-2 across the 16 lanes sharing each token (xor bits 0..3).
#pragma unroll
    for (int s = 0; s < 8; ++s) {
        float v1 = b1[s], v2 = b2[s];
        int   j1 = i1[s], j2 = i2[s];
#pragma unroll
        for (int m = 1; m <= 8; m <<= 1) {
            const float o1 = __shfl_xor(v1, m, 64);
            const int   oj1 = __shfl_xor(j1, m, 64);
            const float o2 = __shfl_xor(v2, m, 64);
            const int   oj2 = __shfl_xor(j2, m, 64);
            if (lt_vi(o1, oj1, v1, j1)) {
                if (lt_vi(v1, j1, o2, oj2)) { v2 = v1; j2 = j1; }
                else                        { v2 = o2; j2 = oj2; }
                v1 = o1; j1 = oj1;
            } else if (lt_vi(o1, oj1, v2, j2)) {
                v2 = o1; j2 = oj1;
            }
        }
        if (ln == 0) {
            const int tl = wv * 32 + (s >> 2) * 16 + kk * 4 + (s & 3);
            Cand[tl][0] = j1;
            Cand[tl][1] = j2;
        }
    }
    __syncthreads();

    // Refinement: bit-exact numpy emulation on 2 candidates (small-live-set
    // single-pass; semantics VERIFIED R5/R6, load order has no fp effect).
    {
        const int token = tid >> 1;          // 0..127
        const int cand  = tid & 1;
        const int code  = Cand[token][cand];
        const float* xr = xh + (size_t)token * ROWS;
        const float* cr = cbh + (size_t)code * DHD;
        float X, C, D;
        refine_exact(xr, cr, X, C, D);
        float d;
        {
#pragma clang fp contract(off)
            const float t = X + C;
            d = t - 2.0f * D;
        }
        const float od = __shfl_xor(d, 1, 64);
        if (cand == 0) {
            const int jA = code;
            const int jB = Cand[token][1];
            const bool pickB = (od < d) || (od == d && jB < jA);
            SIdx[token] = pickB ? jB : jA;
        }
    }
    __syncthreads();

    // Epilogue: gather codebook rows -> out (float4), accumulate (q-x)^2.
    float lacc = 0.f;
    for (int t = wv; t < 128; t += 4) {
        const float4 q4 = *(const float4*)(cbh + (size_t)SIdx[t] * DHD + (lane << 2));
        const float4 x4 = *(const float4*)(xh + (size_t)t * ROWS + (lane << 2));
        const float dx = q4.x - x4.x, dy = q4.y - x4.y;
        const float dz = q4.z - x4.z, dw = q4.w - x4.w;
        lacc += dx * dx + dy * dy + dz * dz + dw * dw;
        *(float4*)(out + 1 + (size_t)(t0 + t) * ROWS + h * DHD + (lane << 2)) = q4;
    }
#pragma unroll
    for (int off = 32; off > 0; off >>= 1) lacc += __shfl_down(lacc, off, 64);
    if (lane == 0) WSum[wv] = lacc;
    __syncthreads();
    if (tid == 0) {
        const float s = WSum[0] + WSum[1] + WSum[2] + WSum[3];
        atomicAdd(out, s * (0.25f / 16777216.f));  // 0.25 * mean
    }
}

// ===========================================================================
// FALLBACK (ws too small): R6 fp32 kernel — verified passing at 558 us.
// ===========================================================================
#define TN 128
#define TK 128
#define KC 16
#define APAD 4
#define BPAD 4

__global__ __launch_bounds__(256, 2) void vq_main_fp32(const float* __restrict__ x,
                                                       const float* __restrict__ cb,
                                                       const float* __restrict__ csq,
                                                       float* __restrict__ out) {
    __shared__ float As[KC][TN + APAD];
    __shared__ float Bs[KC][TK + BPAD];
    __shared__ float Cs[TK];
    __shared__ int   Cand[TN][2];
    __shared__ int   SIdx[TN];
    __shared__ float WSum[4];

    const int tid = threadIdx.x;
    const int h   = blockIdx.y;
    const int t0  = blockIdx.x * TN;
    const int ty  = tid >> 4;
    const int tx  = tid & 15;

    const float* xh  = x  + (size_t)t0 * ROWS + h * DHD;
    const float* cbh = cb + (size_t)h * NK * DHD;

    const int sr = tid >> 1;
    const int sd = (tid & 1) << 3;

    float b1[8], b2[8];
    int   i1[8], i2[8];
#pragma unroll
    for (int r = 0; r < 8; ++r) { b1[r] = FLT_MAX; b2[r] = FLT_MAX; i1[r] = 0; i2[r] = 0; }

    for (int k0 = 0; k0 < NK; k0 += TK) {
        __syncthreads();
        if (tid < TK) Cs[tid] = csq[h * NK + k0 + tid];

        float acc[8][8];
#pragma unroll
        for (int r = 0; r < 8; ++r)
#pragma unroll
            for (int c = 0; c < 8; ++c) acc[r][c] = 0.f;

        for (int d0 = 0; d0 < DHD; d0 += KC) {
            __syncthreads();
            {
                const float* ap = xh + (size_t)sr * ROWS + d0 + sd;
                const float4 a0 = *(const float4*)ap;
                const float4 a1 = *(const float4*)(ap + 4);
                As[sd + 0][sr] = a0.x; As[sd + 1][sr] = a0.y;
                As[sd + 2][sr] = a0.z; As[sd + 3][sr] = a0.w;
                As[sd + 4][sr] = a1.x; As[sd + 5][sr] = a1.y;
                As[sd + 6][sr] = a1.z; As[sd + 7][sr] = a1.w;
            }
            {
                const float* bp = cbh + (size_t)(k0 + sr) * DHD + d0 + sd;
                const float4 b0v = *(const float4*)bp;
                const float4 b1v = *(const float4*)(bp + 4);
                Bs[sd + 0][sr] = b0v.x; Bs[sd + 1][sr] = b0v.y;
                Bs[sd + 2][sr] = b0v.z; Bs[sd + 3][sr] = b0v.w;
                Bs[sd + 4][sr] = b1v.x; Bs[sd + 5][sr] = b1v.y;
                Bs[sd + 6][sr] = b1v.z; Bs[sd + 7][sr] = b1v.w;
            }
            __syncthreads();
#pragma unroll 4
            for (int kc = 0; kc < KC; ++kc) {
                const float4 a0 = *(const float4*)&As[kc][ty << 3];
                const float4 a1 = *(const float4*)&As[kc][(ty << 3) + 4];
                const float4 p0 = *(const float4*)&Bs[kc][tx << 2];
                const float4 p1 = *(const float4*)&Bs[kc][64 + (tx << 2)];
                const float aa[8] = {a0.x, a0.y, a0.z, a0.w, a1.x, a1.y, a1.z, a1.w};
                const float bb[8] = {p0.x, p0.y, p0.z, p0.w, p1.x, p1.y, p1.z, p1.w};
#pragma unroll
                for (int r = 0; r < 8; ++r)
#pragma unroll
                    for (int c = 0; c < 8; ++c)
                        acc[r][c] = fmaf(aa[r], bb[c], acc[r][c]);
            }
        }
#pragma unroll
        for (int r = 0; r < 8; ++r) {
#pragma unroll
            for (int c = 0; c < 8; ++c) {
                const int cc = (c < 4) ? ((tx << 2) + c) : (64 + (tx << 2) + c - 4);
                const float dist = Cs[cc] - 2.f * acc[r][c];
                const int   idx  = k0 + cc;
                if (dist < b1[r]) { b2[r] = b1[r]; i2[r] = i1[r]; b1[r] = dist; i1[r] = idx; }
                else if (dist < b2[r]) { b2[r] = dist; i2[r] = idx; }
            }
        }
    }

#pragma unroll
    for (int r = 0; r < 8; ++r) {
        float v1 = b1[r], v2 = b2[r];
        int   j1 = i1[r], j2 = i2[r];
#pragma unroll
        for (int m = 1; m <= 8; m <<= 1) {
            const float o1 = __shfl_xor(v1, m, 64);
            const int   oj1 = __shfl_xor(j1, m, 64);
            const float o2 = __shfl_xor(v2, m, 64);
            const int   oj2 = __shfl_xor(j2, m, 64);
            if (lt_vi(o1, oj1, v1, j1)) {
                if (lt_vi(v1, j1, o2, oj2)) { v2 = v1; j2 = j1; }
                else                        { v2 = o2; j2 = oj2; }
                v1 = o1; j1 = oj1;
            } else if (lt_vi(o1, oj1, v2, j2)) {
                v2 = o1; j2 = oj1;
            }
        }
        b1[r] = v1; i1[r] = j1; b2[r] = v2; i2[r] = j2;
    }
    if (tx == 0) {
#pragma unroll
        for (int r = 0; r < 8; ++r) {
            Cand[(ty << 3) + r][0] = i1[r];
            Cand[(ty << 3) + r][1] = i2[r];
        }
    }
    __syncthreads();

    {
        const int token = tid >> 1;
        const int cand  = tid & 1;
        const int code  = Cand[token][cand];
        const float* xr = xh + (size_t)token * ROWS;
        const float* cr = cbh + (size_t)code * DHD;
        const float X = np_sq_pairwise256(xr);
        const float C = np_sq_pairwise256(cr);
        const float D = np_dot_seq256(xr, cr);
        float d;
        {
#pragma clang fp contract(off)
            const float t = X + C;
            d = t - 2.0f * D;
        }
        const float od = __shfl_xor(d, 1, 64);
        if (cand == 0) {
            const int jA = code;
            const int jB = Cand[token][1];
            const bool pickB = (od < d) || (od == d && jB < jA);
            SIdx[token] = pickB ? jB : jA;
        }
    }
    __syncthreads();

    const int wav  = tid >> 6;
    const int lane = tid & 63;
    float lacc = 0.f;
    for (int t = wav; t < TN; t += 4) {
        const float4 q4 = *(const float4*)(cbh + (size_t)SIdx[t] * DHD + (lane << 2));
        const float4 x4 = *(const float4*)(xh + (size_t)t * ROWS + (lane << 2));
        const float dx = q4.x - x4.x, dy = q4.y - x4.y;
        const float dz = q4.z - x4.z, dw = q4.w - x4.w;
        lacc += dx * dx + dy * dy + dz * dz + dw * dw;
        *(float4*)(out + 1 + (size_t)(t0 + t) * ROWS + h * DHD + (lane << 2)) = q4;
    }
#pragma unroll
    for (int off = 32; off > 0; off >>= 1) lacc += __shfl_down(lacc, off, 64);
    if (lane == 0) WSum[wav] = lacc;
    __syncthreads();
    if (tid == 0) {
        const float s = WSum[0] + WSum[1] + WSum[2] + WSum[3];
        atomicAdd(out, s * (0.25f / 16777216.f));
    }
}

extern "C" void kernel_launch(void* const* d_in, const int* in_sizes, int n_in,
                              void* d_out, int out_size, void* d_ws, size_t ws_size,
                              hipStream_t stream) {
    const float* x   = (const float*)d_in[0];   // inputs  [16777216]
    const float* cb  = (const float*)d_in[1];   // codebook [1048576]
    float*       out = (float*)d_out;           // [1 + 16777216]
    char*        ws  = (char*)d_ws;
    float*       csq = (float*)(ws + WS_CSQ);

    hipMemsetAsync(d_out, 0, sizeof(float), stream);
    csq_kernel<<<NH * NK, 64, 0, stream>>>(cb, csq);

    if (ws_size >= WS_NEED) {
        uint4* bch = (uint4*)(ws + WS_BH);
        uint4* bcl = (uint4*)(ws + WS_BL);
        cvt_cb_kernel<<<NH * NK / 8, 256, 0, stream>>>(cb, bch, bcl);
        dim3 grid(NTOK / 128, NH);
        vq_mfma<<<grid, 256, 0, stream>>>(x, cb, csq, bch, bcl, out);
    } else {
        dim3 grid(NTOK / TN, NH);
        vq_main_fp32<<<grid, 256, 0, stream>>>(x, cb, csq, out);
    }
}

// Round 5
// 323.961 us; speedup vs baseline: 1.4503x; 1.2010x over previous
//
#include <hip/hip_runtime.h>
#include <cfloat>

// Problem constants (fixed by the reference):
//   inputs  [8,2048,1024] fp32 -> flat [N=16384, H=4, dh=256]
//   codebook[H=4, K=1024, dh=256] fp32
//   out[0] = loss, out[1..] = quantized (16777216 floats)
#define NH    4
#define NK    1024
#define DHD   256
#define NTOK  16384
#define ROWS  (NH * DHD)   // 1024 floats per token row

typedef __attribute__((ext_vector_type(8))) short bf16x8;
typedef __attribute__((ext_vector_type(4))) float f32x4;

// ---------------------------------------------------------------------------
// Workspace layout (bytes). Fast path needs ~4.7 MB; else fp32 fallback.
// ---------------------------------------------------------------------------
#define WS_CSQ  ((size_t)0)
#define WS_BH   ((size_t)16384)                    // cb hi: 4*8*4*1024*16 = 2 MB
#define WS_BL   (WS_BH + (size_t)2097152)          // cb lo: 2 MB
#define WS_CAND (WS_BL + (size_t)2097152)          // cand pairs: 65536*2*4 = 512 KB
#define WS_NEED (WS_CAND + (size_t)524288)

// ---------------------------------------------------------------------------
// bf16 split helpers (round-to-nearest-even)
// ---------------------------------------------------------------------------
__device__ __forceinline__ unsigned short f32_to_bf16_rn(float f) {
    unsigned u = __float_as_uint(f);
    u += 0x7FFFu + ((u >> 16) & 1u);
    return (unsigned short)(u >> 16);
}
__device__ __forceinline__ float bf16_as_f32(unsigned short h) {
    return __uint_as_float(((unsigned)h) << 16);
}

// direct global->LDS DMA, 16B per lane, dest = wave-uniform base + lane*16
__device__ __forceinline__ void gload_lds16(const uint4* g, uint4* l) {
    __builtin_amdgcn_global_load_lds(
        (const __attribute__((address_space(1))) void*)g,
        (__attribute__((address_space(3))) void*)l, 16, 0, 0);
}

// ---------------------------------------------------------------------------
// Kernel 0: per-code squared norms csq[h*NK + k] = sum_d cb[h][k][d]^2 (fp32)
// ---------------------------------------------------------------------------
__global__ __launch_bounds__(64) void csq_kernel(const float* __restrict__ cb,
                                                 float* __restrict__ csq) {
    const int code = blockIdx.x;                 // 0 .. NH*NK-1
    const int lane = threadIdx.x;
    const float4 v = *(const float4*)(cb + (size_t)code * DHD + lane * 4);
    float s = v.x * v.x + v.y * v.y + v.z * v.z + v.w * v.w;
#pragma unroll
    for (int off = 32; off > 0; off >>= 1) s += __shfl_down(s, off, 64);
    if (lane == 0) csq[code] = s;
}

// ---------------------------------------------------------------------------
// cvt_cb: codebook fp32 -> hi/lo bf16, swizzled [h][dc][kk][code] 16B units
// Block 256 threads = 8 codes.
// ---------------------------------------------------------------------------
__global__ __launch_bounds__(256) void cvt_cb_kernel(const float* __restrict__ cb,
                                                     uint4* __restrict__ bch,
                                                     uint4* __restrict__ bcl) {
    const int g = blockIdx.x * 8 + (threadIdx.x >> 5);   // 0..4095
    const int o = threadIdx.x & 31;                      // dh-octet
    const float* src = cb + (size_t)g * DHD + o * 8;
    unsigned wh[4], wl[4];
#pragma unroll
    for (int i = 0; i < 4; ++i) {
        const float f0 = src[2 * i], f1 = src[2 * i + 1];
        const unsigned short h0 = f32_to_bf16_rn(f0);
        const unsigned short h1 = f32_to_bf16_rn(f1);
        const unsigned short l0 = f32_to_bf16_rn(f0 - bf16_as_f32(h0));
        const unsigned short l1 = f32_to_bf16_rn(f1 - bf16_as_f32(h1));
        wh[i] = (unsigned)h0 | ((unsigned)h1 << 16);
        wl[i] = (unsigned)l0 | ((unsigned)l1 << 16);
    }
    const int hh = g >> 10, c = g & 1023, dc = o >> 2, kk = o & 3;
    const size_t unit = (size_t)((hh * 8 + dc) * 4 + kk) * NK + c;
    bch[unit] = make_uint4(wh[0], wh[1], wh[2], wh[3]);
    bcl[unit] = make_uint4(wl[0], wl[1], wl[2], wl[3]);
}

// first-index "less" for (value, index) pairs
__device__ __forceinline__ bool lt_vi(float v, int i, float w, int j) {
    return (v < w) || (v == w && i < j);
}

// ---------------------------------------------------------------------------
// Bit-exact replica of numpy's pairwise sum of squares for n=256 (VERIFIED R5)
// (retained for the fp32 fallback kernel)
// ---------------------------------------------------------------------------
__device__ __forceinline__ float np_sq_pairwise256(const float* __restrict__ a) {
#pragma clang fp contract(off)
    float tot = 0.f;
#pragma unroll
    for (int blk = 0; blk < 2; ++blk) {
        const float* p = a + blk * 128;
        float r0 = p[0] * p[0], r1 = p[1] * p[1], r2 = p[2] * p[2], r3 = p[3] * p[3];
        float r4 = p[4] * p[4], r5 = p[5] * p[5], r6 = p[6] * p[6], r7 = p[7] * p[7];
#pragma clang loop unroll_count(2)
        for (int i = 8; i < 128; i += 8) {
            r0 = r0 + p[i + 0] * p[i + 0];
            r1 = r1 + p[i + 1] * p[i + 1];
            r2 = r2 + p[i + 2] * p[i + 2];
            r3 = r3 + p[i + 3] * p[i + 3];
            r4 = r4 + p[i + 4] * p[i + 4];
            r5 = r5 + p[i + 5] * p[i + 5];
            r6 = r6 + p[i + 6] * p[i + 6];
            r7 = r7 + p[i + 7] * p[i + 7];
        }
        const float res = ((r0 + r1) + (r2 + r3)) + ((r4 + r5) + (r6 + r7));
        tot = (blk == 0) ? res : (tot + res);
    }
    return tot;
}

// Bit-exact replica of np.einsum's sequential fp32 mul+add loop (VERIFIED R5).
__device__ __forceinline__ float np_dot_seq256(const float* __restrict__ a,
                                               const float* __restrict__ b) {
#pragma clang fp contract(off)
    float s = 0.f;
#pragma clang loop unroll_count(4)
    for (int i = 0; i < 256; ++i) s = s + a[i] * b[i];
    return s;
}

// ---------------------------------------------------------------------------
// Single-pass exact refinement, spill-proof codegen:
//  * semantics hardware-verified in R4 (passed, absmax 0.0078125);
//  * zero-init accumulators (exact: squares are never -0, and +0+a==a);
//  * g-loop PARTIALLY unrolled (unroll_count 4) so only ~16 float4 loads are
//    in flight -> small live set, no scratch (R2/R4 spilled via full unroll);
//  * all array indices compile-time (inner j-loops fully unrolled).
// Association order identical to np_sq_pairwise256 / np_dot_seq256.
// ---------------------------------------------------------------------------
__device__ __forceinline__ void refine_exact(const float* __restrict__ xr,
                                             const float* __restrict__ cr,
                                             float& Xo, float& Co, float& Do) {
#pragma clang fp contract(off)
    float s = 0.f;
    float X = 0.f, C = 0.f;
    for (int blk = 0; blk < 2; ++blk) {
        const float4* xq = (const float4*)(xr + blk * 128);
        const float4* cq = (const float4*)(cr + blk * 128);
        float xa[8], ca[8];
#pragma unroll
        for (int j = 0; j < 8; ++j) { xa[j] = 0.f; ca[j] = 0.f; }
#pragma clang loop unroll_count(4)
        for (int g = 0; g < 16; ++g) {
            const float4 a0 = xq[2 * g], a1 = xq[2 * g + 1];
            const float4 b0 = cq[2 * g], b1 = cq[2 * g + 1];
            const float xf[8] = {a0.x, a0.y, a0.z, a0.w, a1.x, a1.y, a1.z, a1.w};
            const float cf[8] = {b0.x, b0.y, b0.z, b0.w, b1.x, b1.y, b1.z, b1.w};
#pragma unroll
            for (int j = 0; j < 8; ++j) {
                xa[j] = xa[j] + xf[j] * xf[j];
                ca[j] = ca[j] + cf[j] * cf[j];
            }
#pragma unroll
            for (int j = 0; j < 8; ++j) s = s + xf[j] * cf[j];
        }
        const float xres = ((xa[0] + xa[1]) + (xa[2] + xa[3])) + ((xa[4] + xa[5]) + (xa[6] + xa[7]));
        const float cres = ((ca[0] + ca[1]) + (ca[2] + ca[3])) + ((ca[4] + ca[5]) + (ca[6] + ca[7]));
        X = (blk == 0) ? xres : (X + xres);
        C = (blk == 0) ? cres : (C + cres);
    }
    Xo = X; Co = C; Do = s;
}

// ===========================================================================
// SCREEN kernel: R1's proven 255us MFMA body, byte-identical k-loop, with the
// tail (refine/epilogue) REMOVED — after the top-2 merge it writes candidate
// pairs to workspace and exits. Separate kernels => separate register files:
// the wide-load refinement can no longer poison this kernel's allocation.
// Grid (NTOK/128, NH), 256 thr / 4 waves; wave w: tokens w*32..w*32+31
// (2 row-tiles of 16). Codes in 64-wide tiles (4 col-tiles), single-buffered.
// dot = hi*hi + hi*lo + lo*hi via mfma_f32_16x16x32_bf16.
// Layouts (doc-verified): A-frag A[m=lane&15][k=(lane>>4)*8+j];
// B-frag (B^T input [code][dh]): B[n=lane&15][k=(lane>>4)*8+j];
// C/D: col(n)=lane&15, row(m)=(lane>>4)*4+reg.
// ===========================================================================
__global__ __launch_bounds__(256, 2) void vq_mfma(const float* __restrict__ x,
                                                  const float* __restrict__ csq,
                                                  const uint4* __restrict__ bch,
                                                  const uint4* __restrict__ bcl,
                                                  int* __restrict__ candw) {
    __shared__ uint4 BsH[2048];    // 64 codes x 256 dh (hi) as [dcKK(32)][code(64)]
    __shared__ uint4 BsL[2048];    // lo
    __shared__ float Cs[NK];       // per-head code norms, loaded once

    const int tid  = threadIdx.x;
    const int h    = blockIdx.y;
    const int t0   = blockIdx.x * 128;
    const int wv   = tid >> 6;
    const int lane = tid & 63;
    const int kk   = lane >> 4;    // 0..3 (k-octet)
    const int ln   = lane & 15;

    // Code norms: whole head once.
#pragma unroll
    for (int i = tid; i < NK; i += 256) Cs[i] = csq[h * NK + i];

    // A fragments: token-stationary, whole dh in registers (hi+lo),
    // converted in-registers from fp32 x (bit-exact split).
    bf16x8 aH[2][8], aL[2][8];
    {
        const int tokb = t0 + wv * 32 + ln;
        const float* xa = x + (size_t)tokb * ROWS + h * DHD + kk * 8;
#pragma unroll
        for (int rt = 0; rt < 2; ++rt) {
#pragma unroll
            for (int dc = 0; dc < 8; ++dc) {
                const float* p = xa + (size_t)(rt * 16) * ROWS + dc * 32;
                const float4 f0 = *(const float4*)p;
                const float4 f1 = *(const float4*)(p + 4);
                const float f[8] = {f0.x, f0.y, f0.z, f0.w, f1.x, f1.y, f1.z, f1.w};
                bf16x8 hv, lv;
#pragma unroll
                for (int j = 0; j < 8; ++j) {
                    const unsigned short hb = f32_to_bf16_rn(f[j]);
                    hv[j] = (short)hb;
                    lv[j] = (short)f32_to_bf16_rn(f[j] - bf16_as_f32(hb));
                }
                aH[rt][dc] = hv;
                aL[rt][dc] = lv;
            }
        }
    }

    float b1[8], b2[8];
    int   i1[8], i2[8];
#pragma unroll
    for (int s = 0; s < 8; ++s) { b1[s] = FLT_MAX; b2[s] = FLT_MAX; i1[s] = 0; i2[s] = 0; }

    for (int k0 = 0; k0 < NK; k0 += 64) {
        __syncthreads();  // protect Bs from previous-iteration readers
        // stage B tile: 2048 hi + 2048 lo units via direct global->LDS DMA.
        // Wave wv, chunk p: LDS elems [p*256+wv*64 ..] <- bch[(h*32+p*4+wv)*NK+k0+lane]
#pragma unroll
        for (int p = 0; p < 8; ++p) {
            const size_t w = (size_t)(h * 32 + p * 4 + wv) * NK + k0 + lane;
            gload_lds16(&bch[w], &BsH[p * 256 + wv * 64]);
            gload_lds16(&bcl[w], &BsL[p * 256 + wv * 64]);
        }
        __syncthreads();  // drains vmcnt(0): DMA'd tile visible

        f32x4 acc[2][4];
#pragma unroll
        for (int rt = 0; rt < 2; ++rt)
#pragma unroll
            for (int ct = 0; ct < 4; ++ct) acc[rt][ct] = (f32x4){0.f, 0.f, 0.f, 0.f};

#pragma unroll
        for (int dc = 0; dc < 8; ++dc) {
#pragma unroll
            for (int ct = 0; ct < 4; ++ct) {
                const int bu = (dc * 4 + kk) * 64 + ct * 16 + ln;
                const bf16x8 bH = *(const bf16x8*)&BsH[bu];
                const bf16x8 bL = *(const bf16x8*)&BsL[bu];
#pragma unroll
                for (int rt = 0; rt < 2; ++rt) {
                    acc[rt][ct] = __builtin_amdgcn_mfma_f32_16x16x32_bf16(aH[rt][dc], bH, acc[rt][ct], 0, 0, 0);
                    acc[rt][ct] = __builtin_amdgcn_mfma_f32_16x16x32_bf16(aH[rt][dc], bL, acc[rt][ct], 0, 0, 0);
                    acc[rt][ct] = __builtin_amdgcn_mfma_f32_16x16x32_bf16(aL[rt][dc], bH, acc[rt][ct], 0, 0, 0);
                }
            }
        }

        // distances (x_sq dropped: per-token constant) + running top-2
#pragma unroll
        for (int rt = 0; rt < 2; ++rt)
#pragma unroll
            for (int ct = 0; ct < 4; ++ct) {
                const float cs   = Cs[k0 + ct * 16 + ln];
                const int   codg = k0 + ct * 16 + ln;
#pragma unroll
                for (int r = 0; r < 4; ++r) {
                    const float dist = cs - 2.f * acc[rt][ct][r];
                    const int   s    = rt * 4 + r;
                    if (dist < b1[s]) { b2[s] = b1[s]; i2[s] = i1[s]; b1[s] = dist; i1[s] = codg; }
                    else if (dist < b2[s]) { b2[s] = dist; i2[s] = codg; }
                }
            }
    }

    // Merge top-2 across the 16 lanes sharing each token (xor bits 0..3),
    // then write candidate pairs straight to workspace.
#pragma unroll
    for (int s = 0; s < 8; ++s) {
        float v1 = b1[s], v2 = b2[s];
        int   j1 = i1[s], j2 = i2[s];
#pragma unroll
        for (int m = 1; m <= 8; m <<= 1) {
            const float o1 = __shfl_xor(v1, m, 64);
            const int   oj1 = __shfl_xor(j1, m, 64);
            const float o2 = __shfl_xor(v2, m, 64);
            const int   oj2 = __shfl_xor(j2, m, 64);
            if (lt_vi(o1, oj1, v1, j1)) {
                if (lt_vi(v1, j1, o2, oj2)) { v2 = v1; j2 = j1; }
                else                        { v2 = o2; j2 = oj2; }
                v1 = o1; j1 = oj1;
            } else if (lt_vi(o1, oj1, v2, j2)) {
                v2 = o1; j2 = oj1;
            }
        }
        if (ln == 0) {
            const int tl  = wv * 32 + (s >> 2) * 16 + kk * 4 + (s & 3);
            const int gid = h * NTOK + t0 + tl;
            candw[2 * gid + 0] = j1;
            candw[2 * gid + 1] = j2;
        }
    }
}

// ===========================================================================
// TAIL kernel: refinement + select + gather + loss. Own register file (the
// whole point of the split). 1 wave per block, 32 (token,head)-rows per
// block, 2 lanes per row (one per candidate). Wave-synchronous: no barriers.
// Grid NTOK*NH/32 = 2048.
// ===========================================================================
__global__ __launch_bounds__(64) void vq_tail(const float* __restrict__ x,
                                              const float* __restrict__ cb,
                                              const int* __restrict__ candw,
                                              float* __restrict__ out) {
    const int lane = threadIdx.x;          // 0..63
    const int rowb = blockIdx.x * 32;      // rows = h*NTOK + t, h uniform in block
    const int h    = rowb >> 14;           // NTOK = 2^14
    const int tb   = rowb & (NTOK - 1);
    const float* cbh = cb + (size_t)h * NK * DHD;

    // Refinement: bit-exact numpy emulation on the 2 candidates.
    const int rloc = lane >> 1;            // 0..31
    const int cand = lane & 1;
    const int row  = rowb + rloc;
    const int t    = tb + rloc;
    const int code = candw[2 * row + cand];
    const float* xr = x + (size_t)t * ROWS + h * DHD;
    const float* cr = cbh + (size_t)code * DHD;
    float X, C, D;
    refine_exact(xr, cr, X, C, D);
    float d;
    {
#pragma clang fp contract(off)
        const float tt = X + C;
        d = tt - 2.0f * D;
    }
    const float od = __shfl_xor(d, 1, 64);
    int sel = code;                        // meaningful in cand==0 lanes
    if (cand == 0) {
        const int jB = candw[2 * row + 1];
        const bool pickB = (od < d) || (od == d && jB < code);
        if (pickB) sel = jB;
    }

    // Epilogue: per row, 64 lanes x float4 = the full 256-float slice.
    float lacc = 0.f;
    for (int r = 0; r < 32; ++r) {
        const int cr_code = __shfl(sel, 2 * r, 64);
        const int tr = tb + r;
        const float4 q4 = *(const float4*)(cbh + (size_t)cr_code * DHD + (lane << 2));
        const float4 x4 = *(const float4*)(x + (size_t)tr * ROWS + h * DHD + (lane << 2));
        const float dx = q4.x - x4.x, dy = q4.y - x4.y;
        const float dz = q4.z - x4.z, dw = q4.w - x4.w;
        lacc += dx * dx + dy * dy + dz * dz + dw * dw;
        *(float4*)(out + 1 + (size_t)tr * ROWS + h * DHD + (lane << 2)) = q4;
    }
#pragma unroll
    for (int off = 32; off > 0; off >>= 1) lacc += __shfl_down(lacc, off, 64);
    if (lane == 0) atomicAdd(out, lacc * (0.25f / 16777216.f));  // 0.25 * mean
}

// ===========================================================================
// FALLBACK (ws too small): R6 fp32 kernel — verified passing at 558 us.
// ===========================================================================
#define TN 128
#define TK 128
#define KC 16
#define APAD 4
#define BPAD 4

__global__ __launch_bounds__(256, 2) void vq_main_fp32(const float* __restrict__ x,
                                                       const float* __restrict__ cb,
                                                       const float* __restrict__ csq,
                                                       float* __restrict__ out) {
    __shared__ float As[KC][TN + APAD];
    __shared__ float Bs[KC][TK + BPAD];
    __shared__ float Cs[TK];
    __shared__ int   Cand[TN][2];
    __shared__ int   SIdx[TN];
    __shared__ float WSum[4];

    const int tid = threadIdx.x;
    const int h   = blockIdx.y;
    const int t0  = blockIdx.x * TN;
    const int ty  = tid >> 4;
    const int tx  = tid & 15;

    const float* xh  = x  + (size_t)t0 * ROWS + h * DHD;
    const float* cbh = cb + (size_t)h * NK * DHD;

    const int sr = tid >> 1;
    const int sd = (tid & 1) << 3;

    float b1[8], b2[8];
    int   i1[8], i2[8];
#pragma unroll
    for (int r = 0; r < 8; ++r) { b1[r] = FLT_MAX; b2[r] = FLT_MAX; i1[r] = 0; i2[r] = 0; }

    for (int k0 = 0; k0 < NK; k0 += TK) {
        __syncthreads();
        if (tid < TK) Cs[tid] = csq[h * NK + k0 + tid];

        float acc[8][8];
#pragma unroll
        for (int r = 0; r < 8; ++r)
#pragma unroll
            for (int c = 0; c < 8; ++c) acc[r][c] = 0.f;

        for (int d0 = 0; d0 < DHD; d0 += KC) {
            __syncthreads();
            {
                const float* ap = xh + (size_t)sr * ROWS + d0 + sd;
                const float4 a0 = *(const float4*)ap;
                const float4 a1 = *(const float4*)(ap + 4);
                As[sd + 0][sr] = a0.x; As[sd + 1][sr] = a0.y;
                As[sd + 2][sr] = a0.z; As[sd + 3][sr] = a0.w;
                As[sd + 4][sr] = a1.x; As[sd + 5][sr] = a1.y;
                As[sd + 6][sr] = a1.z; As[sd + 7][sr] = a1.w;
            }
            {
                const float* bp = cbh + (size_t)(k0 + sr) * DHD + d0 + sd;
                const float4 b0v = *(const float4*)bp;
                const float4 b1v = *(const float4*)(bp + 4);
                Bs[sd + 0][sr] = b0v.x; Bs[sd + 1][sr] = b0v.y;
                Bs[sd + 2][sr] = b0v.z; Bs[sd + 3][sr] = b0v.w;
                Bs[sd + 4][sr] = b1v.x; Bs[sd + 5][sr] = b1v.y;
                Bs[sd + 6][sr] = b1v.z; Bs[sd + 7][sr] = b1v.w;
            }
            __syncthreads();
#pragma unroll 4
            for (int kc = 0; kc < KC; ++kc) {
                const float4 a0 = *(const float4*)&As[kc][ty << 3];
                const float4 a1 = *(const float4*)&As[kc][(ty << 3) + 4];
                const float4 p0 = *(const float4*)&Bs[kc][tx << 2];
                const float4 p1 = *(const float4*)&Bs[kc][64 + (tx << 2)];
                const float aa[8] = {a0.x, a0.y, a0.z, a0.w, a1.x, a1.y, a1.z, a1.w};
                const float bb[8] = {p0.x, p0.y, p0.z, p0.w, p1.x, p1.y, p1.z, p1.w};
#pragma unroll
                for (int r = 0; r < 8; ++r)
#pragma unroll
                    for (int c = 0; c < 8; ++c)
                        acc[r][c] = fmaf(aa[r], bb[c], acc[r][c]);
            }
        }
#pragma unroll
        for (int r = 0; r < 8; ++r) {
#pragma unroll
            for (int c = 0; c < 8; ++c) {
                const int cc = (c < 4) ? ((tx << 2) + c) : (64 + (tx << 2) + c - 4);
                const float dist = Cs[cc] - 2.f * acc[r][c];
                const int   idx  = k0 + cc;
                if (dist < b1[r]) { b2[r] = b1[r]; i2[r] = i1[r]; b1[r] = dist; i1[r] = idx; }
                else if (dist < b2[r]) { b2[r] = dist; i2[r] = idx; }
            }
        }
    }

#pragma unroll
    for (int r = 0; r < 8; ++r) {
        float v1 = b1[r], v2 = b2[r];
        int   j1 = i1[r], j2 = i2[r];
#pragma unroll
        for (int m = 1; m <= 8; m <<= 1) {
            const float o1 = __shfl_xor(v1, m, 64);
            const int   oj1 = __shfl_xor(j1, m, 64);
            const float o2 = __shfl_xor(v2, m, 64);
            const int   oj2 = __shfl_xor(j2, m, 64);
            if (lt_vi(o1, oj1, v1, j1)) {
                if (lt_vi(v1, j1, o2, oj2)) { v2 = v1; j2 = j1; }
                else                        { v2 = o2; j2 = oj2; }
                v1 = o1; j1 = oj1;
            } else if (lt_vi(o1, oj1, v2, j2)) {
                v2 = o1; j2 = oj1;
            }
        }
        b1[r] = v1; i1[r] = j1; b2[r] = v2; i2[r] = j2;
    }
    if (tx == 0) {
#pragma unroll
        for (int r = 0; r < 8; ++r) {
            Cand[(ty << 3) + r][0] = i1[r];
            Cand[(ty << 3) + r][1] = i2[r];
        }
    }
    __syncthreads();

    {
        const int token = tid >> 1;
        const int cand  = tid & 1;
        const int code  = Cand[token][cand];
        const float* xr = xh + (size_t)token * ROWS;
        const float* cr = cbh + (size_t)code * DHD;
        const float X = np_sq_pairwise256(xr);
        const float C = np_sq_pairwise256(cr);
        const float D = np_dot_seq256(xr, cr);
        float d;
        {
#pragma clang fp contract(off)
            const float t = X + C;
            d = t - 2.0f * D;
        }
        const float od = __shfl_xor(d, 1, 64);
        if (cand == 0) {
            const int jA = code;
            const int jB = Cand[token][1];
            const bool pickB = (od < d) || (od == d && jB < jA);
            SIdx[token] = pickB ? jB : jA;
        }
    }
    __syncthreads();

    const int wav  = tid >> 6;
    const int lane = tid & 63;
    float lacc = 0.f;
    for (int t = wav; t < TN; t += 4) {
        const float4 q4 = *(const float4*)(cbh + (size_t)SIdx[t] * DHD + (lane << 2));
        const float4 x4 = *(const float4*)(xh + (size_t)t * ROWS + (lane << 2));
        const float dx = q4.x - x4.x, dy = q4.y - x4.y;
        const float dz = q4.z - x4.z, dw = q4.w - x4.w;
        lacc += dx * dx + dy * dy + dz * dz + dw * dw;
        *(float4*)(out + 1 + (size_t)(t0 + t) * ROWS + h * DHD + (lane << 2)) = q4;
    }
#pragma unroll
    for (int off = 32; off > 0; off >>= 1) lacc += __shfl_down(lacc, off, 64);
    if (lane == 0) WSum[wav] = lacc;
    __syncthreads();
    if (tid == 0) {
        const float s = WSum[0] + WSum[1] + WSum[2] + WSum[3];
        atomicAdd(out, s * (0.25f / 16777216.f));
    }
}

extern "C" void kernel_launch(void* const* d_in, const int* in_sizes, int n_in,
                              void* d_out, int out_size, void* d_ws, size_t ws_size,
                              hipStream_t stream) {
    const float* x   = (const float*)d_in[0];   // inputs  [16777216]
    const float* cb  = (const float*)d_in[1];   // codebook [1048576]
    float*       out = (float*)d_out;           // [1 + 16777216]
    char*        ws  = (char*)d_ws;
    float*       csq = (float*)(ws + WS_CSQ);

    hipMemsetAsync(d_out, 0, sizeof(float), stream);
    csq_kernel<<<NH * NK, 64, 0, stream>>>(cb, csq);

    if (ws_size >= WS_NEED) {
        uint4* bch   = (uint4*)(ws + WS_BH);
        uint4* bcl   = (uint4*)(ws + WS_BL);
        int*   candw = (int*)(ws + WS_CAND);
        cvt_cb_kernel<<<NH * NK / 8, 256, 0, stream>>>(cb, bch, bcl);
        dim3 grid(NTOK / 128, NH);
        vq_mfma<<<grid, 256, 0, stream>>>(x, csq, bch, bcl, candw);
        vq_tail<<<NTOK * NH / 32, 64, 0, stream>>>(x, cb, candw, out);
    } else {
        dim3 grid(NTOK / TN, NH);
        vq_main_fp32<<<grid, 256, 0, stream>>>(x, cb, csq, out);
    }
}

// Round 6
// 308.236 us; speedup vs baseline: 1.5242x; 1.0510x over previous
//
#include <hip/hip_runtime.h>
#include <cfloat>

// Problem constants (fixed by the reference):
//   inputs  [8,2048,1024] fp32 -> flat [N=16384, H=4, dh=256]
//   codebook[H=4, K=1024, dh=256] fp32
//   out[0] = loss, out[1..] = quantized (16777216 floats)
#define NH    4
#define NK    1024
#define DHD   256
#define NTOK  16384
#define ROWS  (NH * DHD)   // 1024 floats per token row

typedef __attribute__((ext_vector_type(8))) short bf16x8;
typedef __attribute__((ext_vector_type(4))) float f32x4;

// ---------------------------------------------------------------------------
// Workspace layout (bytes). Fast path needs ~4.7 MB; else fp32 fallback.
// ---------------------------------------------------------------------------
#define WS_CSQ  ((size_t)0)
#define WS_BH   ((size_t)16384)                    // cb hi: 4*8*4*1024*16 = 2 MB
#define WS_BL   (WS_BH + (size_t)2097152)          // cb lo: 2 MB
#define WS_CAND (WS_BL + (size_t)2097152)          // cand pairs: 65536*2*4 = 512 KB
#define WS_NEED (WS_CAND + (size_t)524288)

// ---------------------------------------------------------------------------
// bf16 split helpers (round-to-nearest-even)
// ---------------------------------------------------------------------------
__device__ __forceinline__ unsigned short f32_to_bf16_rn(float f) {
    unsigned u = __float_as_uint(f);
    u += 0x7FFFu + ((u >> 16) & 1u);
    return (unsigned short)(u >> 16);
}
__device__ __forceinline__ float bf16_as_f32(unsigned short h) {
    return __uint_as_float(((unsigned)h) << 16);
}

// direct global->LDS DMA, 16B per lane, dest = wave-uniform base + lane*16
__device__ __forceinline__ void gload_lds16(const uint4* g, uint4* l) {
    __builtin_amdgcn_global_load_lds(
        (const __attribute__((address_space(1))) void*)g,
        (__attribute__((address_space(3))) void*)l, 16, 0, 0);
}

// ---------------------------------------------------------------------------
// Kernel 0 (FALLBACK PATH ONLY): per-code squared norms.
// Fast path computes csq inside cvt_cb_kernel.
// ---------------------------------------------------------------------------
__global__ __launch_bounds__(64) void csq_kernel(const float* __restrict__ cb,
                                                 float* __restrict__ csq) {
    const int code = blockIdx.x;                 // 0 .. NH*NK-1
    const int lane = threadIdx.x;
    const float4 v = *(const float4*)(cb + (size_t)code * DHD + lane * 4);
    float s = v.x * v.x + v.y * v.y + v.z * v.z + v.w * v.w;
#pragma unroll
    for (int off = 32; off > 0; off >>= 1) s += __shfl_down(s, off, 64);
    if (lane == 0) csq[code] = s;
}

// ---------------------------------------------------------------------------
// cvt_cb: codebook fp32 -> hi/lo bf16, swizzled [h][dc][kk][code] 16B units,
// PLUS per-code squared norms (fp32) — csq only screens; refine recomputes
// exactly, so the reduction-order change vs csq_kernel is harmless.
// Block 256 threads = 8 codes (32 lanes per code).
// ---------------------------------------------------------------------------
__global__ __launch_bounds__(256) void cvt_cb_kernel(const float* __restrict__ cb,
                                                     uint4* __restrict__ bch,
                                                     uint4* __restrict__ bcl,
                                                     float* __restrict__ csq) {
    const int g = blockIdx.x * 8 + (threadIdx.x >> 5);   // 0..4095
    const int o = threadIdx.x & 31;                      // dh-octet
    const float* src = cb + (size_t)g * DHD + o * 8;
    unsigned wh[4], wl[4];
    float s = 0.f;
#pragma unroll
    for (int i = 0; i < 4; ++i) {
        const float f0 = src[2 * i], f1 = src[2 * i + 1];
        s += f0 * f0 + f1 * f1;
        const unsigned short h0 = f32_to_bf16_rn(f0);
        const unsigned short h1 = f32_to_bf16_rn(f1);
        const unsigned short l0 = f32_to_bf16_rn(f0 - bf16_as_f32(h0));
        const unsigned short l1 = f32_to_bf16_rn(f1 - bf16_as_f32(h1));
        wh[i] = (unsigned)h0 | ((unsigned)h1 << 16);
        wl[i] = (unsigned)l0 | ((unsigned)l1 << 16);
    }
    const int hh = g >> 10, c = g & 1023, dc = o >> 2, kk = o & 3;
    const size_t unit = (size_t)((hh * 8 + dc) * 4 + kk) * NK + c;
    bch[unit] = make_uint4(wh[0], wh[1], wh[2], wh[3]);
    bcl[unit] = make_uint4(wl[0], wl[1], wl[2], wl[3]);
    // 32-lane reduction for this code's norm
#pragma unroll
    for (int m = 16; m > 0; m >>= 1) s += __shfl_xor(s, m, 32);
    if (o == 0) csq[g] = s;
}

// first-index "less" for (value, index) pairs
__device__ __forceinline__ bool lt_vi(float v, int i, float w, int j) {
    return (v < w) || (v == w && i < j);
}

// ---------------------------------------------------------------------------
// Bit-exact replica of numpy's pairwise sum of squares for n=256 (VERIFIED R5)
// (retained for the fp32 fallback kernel)
// ---------------------------------------------------------------------------
__device__ __forceinline__ float np_sq_pairwise256(const float* __restrict__ a) {
#pragma clang fp contract(off)
    float tot = 0.f;
#pragma unroll
    for (int blk = 0; blk < 2; ++blk) {
        const float* p = a + blk * 128;
        float r0 = p[0] * p[0], r1 = p[1] * p[1], r2 = p[2] * p[2], r3 = p[3] * p[3];
        float r4 = p[4] * p[4], r5 = p[5] * p[5], r6 = p[6] * p[6], r7 = p[7] * p[7];
#pragma clang loop unroll_count(2)
        for (int i = 8; i < 128; i += 8) {
            r0 = r0 + p[i + 0] * p[i + 0];
            r1 = r1 + p[i + 1] * p[i + 1];
            r2 = r2 + p[i + 2] * p[i + 2];
            r3 = r3 + p[i + 3] * p[i + 3];
            r4 = r4 + p[i + 4] * p[i + 4];
            r5 = r5 + p[i + 5] * p[i + 5];
            r6 = r6 + p[i + 6] * p[i + 6];
            r7 = r7 + p[i + 7] * p[i + 7];
        }
        const float res = ((r0 + r1) + (r2 + r3)) + ((r4 + r5) + (r6 + r7));
        tot = (blk == 0) ? res : (tot + res);
    }
    return tot;
}

// Bit-exact replica of np.einsum's sequential fp32 mul+add loop (VERIFIED R5).
__device__ __forceinline__ float np_dot_seq256(const float* __restrict__ a,
                                               const float* __restrict__ b) {
#pragma clang fp contract(off)
    float s = 0.f;
#pragma clang loop unroll_count(4)
    for (int i = 0; i < 256; ++i) s = s + a[i] * b[i];
    return s;
}

// ---------------------------------------------------------------------------
// Single-pass exact refinement, spill-proof codegen (R5 hardware-verified:
// passed, WRITE_SIZE clean in its own kernel). Partial unroll keeps ~16
// float4 loads in flight; all indices compile-time.
// Association order identical to np_sq_pairwise256 / np_dot_seq256.
// ---------------------------------------------------------------------------
__device__ __forceinline__ void refine_exact(const float* __restrict__ xr,
                                             const float* __restrict__ cr,
                                             float& Xo, float& Co, float& Do) {
#pragma clang fp contract(off)
    float s = 0.f;
    float X = 0.f, C = 0.f;
    for (int blk = 0; blk < 2; ++blk) {
        const float4* xq = (const float4*)(xr + blk * 128);
        const float4* cq = (const float4*)(cr + blk * 128);
        float xa[8], ca[8];
#pragma unroll
        for (int j = 0; j < 8; ++j) { xa[j] = 0.f; ca[j] = 0.f; }
#pragma clang loop unroll_count(4)
        for (int g = 0; g < 16; ++g) {
            const float4 a0 = xq[2 * g], a1 = xq[2 * g + 1];
            const float4 b0 = cq[2 * g], b1 = cq[2 * g + 1];
            const float xf[8] = {a0.x, a0.y, a0.z, a0.w, a1.x, a1.y, a1.z, a1.w};
            const float cf[8] = {b0.x, b0.y, b0.z, b0.w, b1.x, b1.y, b1.z, b1.w};
#pragma unroll
            for (int j = 0; j < 8; ++j) {
                xa[j] = xa[j] + xf[j] * xf[j];
                ca[j] = ca[j] + cf[j] * cf[j];
            }
#pragma unroll
            for (int j = 0; j < 8; ++j) s = s + xf[j] * cf[j];
        }
        const float xres = ((xa[0] + xa[1]) + (xa[2] + xa[3])) + ((xa[4] + xa[5]) + (xa[6] + xa[7]));
        const float cres = ((ca[0] + ca[1]) + (ca[2] + ca[3])) + ((ca[4] + ca[5]) + (ca[6] + ca[7]));
        X = (blk == 0) ? xres : (X + xres);
        C = (blk == 0) ? cres : (C + cres);
    }
    Xo = X; Co = C; Do = s;
}

// ===========================================================================
// SCREEN kernel: R5's verified body with KT=32 single-buffered B tiles.
// LDS 36.9 KB -> 4 blocks/CU (16 waves/CU) at VGPR<=128; no forced occupancy
// bound (R3 lesson: forcing triggers pathological allocation).
// Grid (NTOK/128, NH), 256 thr / 4 waves; wave w: tokens w*32..w*32+31
// (2 row-tiles of 16). Codes in 32-wide tiles (2 col-tiles) — staging and
// indexing verified in R4 (numerically passing).
// dot = hi*hi + hi*lo + lo*hi via mfma_f32_16x16x32_bf16.
// Layouts (doc-verified): A-frag A[m=lane&15][k=(lane>>4)*8+j];
// B-frag (B^T input [code][dh]): B[n=lane&15][k=(lane>>4)*8+j];
// C/D: col(n)=lane&15, row(m)=(lane>>4)*4+reg.
// ===========================================================================
#define KT 32            // codes per tile
#define NTIL (NK / KT)   // 32 tiles

__global__ __launch_bounds__(256, 2) void vq_mfma(const float* __restrict__ x,
                                                  const float* __restrict__ csq,
                                                  const uint4* __restrict__ bch,
                                                  const uint4* __restrict__ bcl,
                                                  int* __restrict__ candw) {
    __shared__ uint4 BsH[1024];    // 32 codes x 256 dh (hi) as [dcKK(32)][code(32)]
    __shared__ uint4 BsL[1024];    // lo
    __shared__ float Cs[NK];       // per-head code norms, loaded once

    const int tid  = threadIdx.x;
    const int h    = blockIdx.y;
    const int t0   = blockIdx.x * 128;
    const int wv   = tid >> 6;
    const int lane = tid & 63;
    const int kk   = lane >> 4;    // 0..3 (k-octet)
    const int ln   = lane & 15;

    // Code norms: whole head once.
#pragma unroll
    for (int i = tid; i < NK; i += 256) Cs[i] = csq[h * NK + i];

    // A fragments: token-stationary, whole dh in registers (hi+lo),
    // converted in-registers from fp32 x (bit-exact split).
    bf16x8 aH[2][8], aL[2][8];
    {
        const int tokb = t0 + wv * 32 + ln;
        const float* xa = x + (size_t)tokb * ROWS + h * DHD + kk * 8;
#pragma unroll
        for (int rt = 0; rt < 2; ++rt) {
#pragma unroll
            for (int dc = 0; dc < 8; ++dc) {
                const float* p = xa + (size_t)(rt * 16) * ROWS + dc * 32;
                const float4 f0 = *(const float4*)p;
                const float4 f1 = *(const float4*)(p + 4);
                const float f[8] = {f0.x, f0.y, f0.z, f0.w, f1.x, f1.y, f1.z, f1.w};
                bf16x8 hv, lv;
#pragma unroll
                for (int j = 0; j < 8; ++j) {
                    const unsigned short hb = f32_to_bf16_rn(f[j]);
                    hv[j] = (short)hb;
                    lv[j] = (short)f32_to_bf16_rn(f[j] - bf16_as_f32(hb));
                }
                aH[rt][dc] = hv;
                aL[rt][dc] = lv;
            }
        }
    }

    float b1[8], b2[8];
    int   i1[8], i2[8];
#pragma unroll
    for (int s = 0; s < 8; ++s) { b1[s] = FLT_MAX; b2[s] = FLT_MAX; i1[s] = 0; i2[s] = 0; }

    for (int t = 0; t < NTIL; ++t) {
        const int k0 = t * KT;
        __syncthreads();  // protect Bs from previous-iteration readers
        // stage B tile: 1024 hi + 1024 lo units via direct global->LDS DMA.
        // Wave wv, chunk q=wv*4+p: lane l -> row 2q+(l>>5), col l&31;
        // LDS dest unit q*64+l == row*32+col (linear match, wave-uniform base).
#pragma unroll
        for (int p = 0; p < 4; ++p) {
            const int q   = wv * 4 + p;
            const int row = 2 * q + (lane >> 5);
            const size_t w = (size_t)(h * 32 + row) * NK + k0 + (lane & 31);
            gload_lds16(&bch[w], &BsH[q * 64]);
            gload_lds16(&bcl[w], &BsL[q * 64]);
        }
        __syncthreads();  // drains vmcnt(0): DMA'd tile visible

        f32x4 acc[2][2];
#pragma unroll
        for (int rt = 0; rt < 2; ++rt)
#pragma unroll
            for (int ct = 0; ct < 2; ++ct) acc[rt][ct] = (f32x4){0.f, 0.f, 0.f, 0.f};

#pragma unroll
        for (int dc = 0; dc < 8; ++dc) {
#pragma unroll
            for (int ct = 0; ct < 2; ++ct) {
                const int bu = (dc * 4 + kk) * 32 + ct * 16 + ln;
                const bf16x8 bH = *(const bf16x8*)&BsH[bu];
                const bf16x8 bL = *(const bf16x8*)&BsL[bu];
#pragma unroll
                for (int rt = 0; rt < 2; ++rt) {
                    acc[rt][ct] = __builtin_amdgcn_mfma_f32_16x16x32_bf16(aH[rt][dc], bH, acc[rt][ct], 0, 0, 0);
                    acc[rt][ct] = __builtin_amdgcn_mfma_f32_16x16x32_bf16(aH[rt][dc], bL, acc[rt][ct], 0, 0, 0);
                    acc[rt][ct] = __builtin_amdgcn_mfma_f32_16x16x32_bf16(aL[rt][dc], bH, acc[rt][ct], 0, 0, 0);
                }
            }
        }

        // distances (x_sq dropped: per-token constant) + running top-2
#pragma unroll
        for (int rt = 0; rt < 2; ++rt)
#pragma unroll
            for (int ct = 0; ct < 2; ++ct) {
                const float cs   = Cs[k0 + ct * 16 + ln];
                const int   codg = k0 + ct * 16 + ln;
#pragma unroll
                for (int r = 0; r < 4; ++r) {
                    const float dist = cs - 2.f * acc[rt][ct][r];
                    const int   s    = rt * 4 + r;
                    if (dist < b1[s]) { b2[s] = b1[s]; i2[s] = i1[s]; b1[s] = dist; i1[s] = codg; }
                    else if (dist < b2[s]) { b2[s] = dist; i2[s] = codg; }
                }
            }
    }

    // Merge top-2 across the 16 lanes sharing each token (xor bits 0..3),
    // then write candidate pairs straight to workspace.
#pragma unroll
    for (int s = 0; s < 8; ++s) {
        float v1 = b1[s], v2 = b2[s];
        int   j1 = i1[s], j2 = i2[s];
#pragma unroll
        for (int m = 1; m <= 8; m <<= 1) {
            const float o1 = __shfl_xor(v1, m, 64);
            const int   oj1 = __shfl_xor(j1, m, 64);
            const float o2 = __shfl_xor(v2, m, 64);
            const int   oj2 = __shfl_xor(j2, m, 64);
            if (lt_vi(o1, oj1, v1, j1)) {
                if (lt_vi(v1, j1, o2, oj2)) { v2 = v1; j2 = j1; }
                else                        { v2 = o2; j2 = oj2; }
                v1 = o1; j1 = oj1;
            } else if (lt_vi(o1, oj1, v2, j2)) {
                v2 = o1; j2 = oj1;
            }
        }
        if (ln == 0) {
            const int tl  = wv * 32 + (s >> 2) * 16 + kk * 4 + (s & 3);
            const int gid = h * NTOK + t0 + tl;
            candw[2 * gid + 0] = j1;
            candw[2 * gid + 1] = j2;
        }
    }
}

// ===========================================================================
// TAIL kernel: refinement + select + gather + loss, own register file.
// Loss now comes from refine's exact sums: for the selected code,
// sum((q-x)^2) == X + C - 2D (algebraic identity on the exact fp32 values)
// -> the epilogue no longer re-reads x (saves 64 MB of HBM traffic).
// 1 wave per block, 32 (token,head)-rows, 2 lanes per row. Grid 2048.
// ===========================================================================
__global__ __launch_bounds__(64) void vq_tail(const float* __restrict__ x,
                                              const float* __restrict__ cb,
                                              const int* __restrict__ candw,
                                              float* __restrict__ out) {
    const int lane = threadIdx.x;          // 0..63
    const int rowb = blockIdx.x * 32;      // rows = h*NTOK + t, h uniform in block
    const int h    = rowb >> 14;           // NTOK = 2^14
    const int tb   = rowb & (NTOK - 1);
    const float* cbh = cb + (size_t)h * NK * DHD;

    // Refinement: bit-exact numpy emulation on the 2 candidates.
    const int rloc = lane >> 1;            // 0..31
    const int cand = lane & 1;
    const int row  = rowb + rloc;
    const int t    = tb + rloc;
    const int code = candw[2 * row + cand];
    const float* xr = x + (size_t)t * ROWS + h * DHD;
    const float* cr = cbh + (size_t)code * DHD;
    float X, C, D;
    refine_exact(xr, cr, X, C, D);
    float d;
    {
#pragma clang fp contract(off)
        const float tt = X + C;
        d = tt - 2.0f * D;
    }
    const float od = __shfl_xor(d, 1, 64);
    int   sel  = code;                     // meaningful in cand==0 lanes
    float lacc = 0.f;
    if (cand == 0) {
        const int jB = candw[2 * row + 1];
        const bool pickB = (od < d) || (od == d && jB < code);
        sel  = pickB ? jB : code;
        lacc = pickB ? od : d;             // selected (q-x)^2 row-sum, exact
    }

    // Epilogue: per row, 64 lanes x float4 = the full 256-float slice.
    for (int r = 0; r < 32; ++r) {
        const int cr_code = __shfl(sel, 2 * r, 64);
        const int tr = tb + r;
        const float4 q4 = *(const float4*)(cbh + (size_t)cr_code * DHD + (lane << 2));
        *(float4*)(out + 1 + (size_t)tr * ROWS + h * DHD + (lane << 2)) = q4;
    }
#pragma unroll
    for (int off = 32; off > 0; off >>= 1) lacc += __shfl_down(lacc, off, 64);
    if (lane == 0) atomicAdd(out, lacc * (0.25f / 16777216.f));  // 0.25 * mean
}

// ===========================================================================
// FALLBACK (ws too small): R6 fp32 kernel — verified passing at 558 us.
// ===========================================================================
#define TN 128
#define TK 128
#define KC 16
#define APAD 4
#define BPAD 4

__global__ __launch_bounds__(256, 2) void vq_main_fp32(const float* __restrict__ x,
                                                       const float* __restrict__ cb,
                                                       const float* __restrict__ csq,
                                                       float* __restrict__ out) {
    __shared__ float As[KC][TN + APAD];
    __shared__ float Bs[KC][TK + BPAD];
    __shared__ float Cs[TK];
    __shared__ int   Cand[TN][2];
    __shared__ int   SIdx[TN];
    __shared__ float WSum[4];

    const int tid = threadIdx.x;
    const int h   = blockIdx.y;
    const int t0  = blockIdx.x * TN;
    const int ty  = tid >> 4;
    const int tx  = tid & 15;

    const float* xh  = x  + (size_t)t0 * ROWS + h * DHD;
    const float* cbh = cb + (size_t)h * NK * DHD;

    const int sr = tid >> 1;
    const int sd = (tid & 1) << 3;

    float b1[8], b2[8];
    int   i1[8], i2[8];
#pragma unroll
    for (int r = 0; r < 8; ++r) { b1[r] = FLT_MAX; b2[r] = FLT_MAX; i1[r] = 0; i2[r] = 0; }

    for (int k0 = 0; k0 < NK; k0 += TK) {
        __syncthreads();
        if (tid < TK) Cs[tid] = csq[h * NK + k0 + tid];

        float acc[8][8];
#pragma unroll
        for (int r = 0; r < 8; ++r)
#pragma unroll
            for (int c = 0; c < 8; ++c) acc[r][c] = 0.f;

        for (int d0 = 0; d0 < DHD; d0 += KC) {
            __syncthreads();
            {
                const float* ap = xh + (size_t)sr * ROWS + d0 + sd;
                const float4 a0 = *(const float4*)ap;
                const float4 a1 = *(const float4*)(ap + 4);
                As[sd + 0][sr] = a0.x; As[sd + 1][sr] = a0.y;
                As[sd + 2][sr] = a0.z; As[sd + 3][sr] = a0.w;
                As[sd + 4][sr] = a1.x; As[sd + 5][sr] = a1.y;
                As[sd + 6][sr] = a1.z; As[sd + 7][sr] = a1.w;
            }
            {
                const float* bp = cbh + (size_t)(k0 + sr) * DHD + d0 + sd;
                const float4 b0v = *(const float4*)bp;
                const float4 b1v = *(const float4*)(bp + 4);
                Bs[sd + 0][sr] = b0v.x; Bs[sd + 1][sr] = b0v.y;
                Bs[sd + 2][sr] = b0v.z; Bs[sd + 3][sr] = b0v.w;
                Bs[sd + 4][sr] = b1v.x; Bs[sd + 5][sr] = b1v.y;
                Bs[sd + 6][sr] = b1v.z; Bs[sd + 7][sr] = b1v.w;
            }
            __syncthreads();
#pragma unroll 4
            for (int kc = 0; kc < KC; ++kc) {
                const float4 a0 = *(const float4*)&As[kc][ty << 3];
                const float4 a1 = *(const float4*)&As[kc][(ty << 3) + 4];
                const float4 p0 = *(const float4*)&Bs[kc][tx << 2];
                const float4 p1 = *(const float4*)&Bs[kc][64 + (tx << 2)];
                const float aa[8] = {a0.x, a0.y, a0.z, a0.w, a1.x, a1.y, a1.z, a1.w};
                const float bb[8] = {p0.x, p0.y, p0.z, p0.w, p1.x, p1.y, p1.z, p1.w};
#pragma unroll
                for (int r = 0; r < 8; ++r)
#pragma unroll
                    for (int c = 0; c < 8; ++c)
                        acc[r][c] = fmaf(aa[r], bb[c], acc[r][c]);
            }
        }
#pragma unroll
        for (int r = 0; r < 8; ++r) {
#pragma unroll
            for (int c = 0; c < 8; ++c) {
                const int cc = (c < 4) ? ((tx << 2) + c) : (64 + (tx << 2) + c - 4);
                const float dist = Cs[cc] - 2.f * acc[r][c];
                const int   idx  = k0 + cc;
                if (dist < b1[r]) { b2[r] = b1[r]; i2[r] = i1[r]; b1[r] = dist; i1[r] = idx; }
                else if (dist < b2[r]) { b2[r] = dist; i2[r] = idx; }
            }
        }
    }

#pragma unroll
    for (int r = 0; r < 8; ++r) {
        float v1 = b1[r], v2 = b2[r];
        int   j1 = i1[r], j2 = i2[r];
#pragma unroll
        for (int m = 1; m <= 8; m <<= 1) {
            const float o1 = __shfl_xor(v1, m, 64);
            const int   oj1 = __shfl_xor(j1, m, 64);
            const float o2 = __shfl_xor(v2, m, 64);
            const int   oj2 = __shfl_xor(j2, m, 64);
            if (lt_vi(o1, oj1, v1, j1)) {
                if (lt_vi(v1, j1, o2, oj2)) { v2 = v1; j2 = j1; }
                else                        { v2 = o2; j2 = oj2; }
                v1 = o1; j1 = oj1;
            } else if (lt_vi(o1, oj1, v2, j2)) {
                v2 = o1; j2 = oj1;
            }
        }
        b1[r] = v1; i1[r] = j1; b2[r] = v2; i2[r] = j2;
    }
    if (tx == 0) {
#pragma unroll
        for (int r = 0; r < 8; ++r) {
            Cand[(ty << 3) + r][0] = i1[r];
            Cand[(ty << 3) + r][1] = i2[r];
        }
    }
    __syncthreads();

    {
        const int token = tid >> 1;
        const int cand  = tid & 1;
        const int code  = Cand[token][cand];
        const float* xr = xh + (size_t)token * ROWS;
        const float* cr = cbh + (size_t)code * DHD;
        const float X = np_sq_pairwise256(xr);
        const float C = np_sq_pairwise256(cr);
        const float D = np_dot_seq256(xr, cr);
        float d;
        {
#pragma clang fp contract(off)
            const float t = X + C;
            d = t - 2.0f * D;
        }
        const float od = __shfl_xor(d, 1, 64);
        if (cand == 0) {
            const int jA = code;
            const int jB = Cand[token][1];
            const bool pickB = (od < d) || (od == d && jB < jA);
            SIdx[token] = pickB ? jB : jA;
        }
    }
    __syncthreads();

    const int wav  = tid >> 6;
    const int lane = tid & 63;
    float lacc = 0.f;
    for (int t = wav; t < TN; t += 4) {
        const float4 q4 = *(const float4*)(cbh + (size_t)SIdx[t] * DHD + (lane << 2));
        const float4 x4 = *(const float4*)(xh + (size_t)t * ROWS + (lane << 2));
        const float dx = q4.x - x4.x, dy = q4.y - x4.y;
        const float dz = q4.z - x4.z, dw = q4.w - x4.w;
        lacc += dx * dx + dy * dy + dz * dz + dw * dw;
        *(float4*)(out + 1 + (size_t)(t0 + t) * ROWS + h * DHD + (lane << 2)) = q4;
    }
#pragma unroll
    for (int off = 32; off > 0; off >>= 1) lacc += __shfl_down(lacc, off, 64);
    if (lane == 0) WSum[wav] = lacc;
    __syncthreads();
    if (tid == 0) {
        const float s = WSum[0] + WSum[1] + WSum[2] + WSum[3];
        atomicAdd(out, s * (0.25f / 16777216.f));
    }
}

extern "C" void kernel_launch(void* const* d_in, const int* in_sizes, int n_in,
                              void* d_out, int out_size, void* d_ws, size_t ws_size,
                              hipStream_t stream) {
    const float* x   = (const float*)d_in[0];   // inputs  [16777216]
    const float* cb  = (const float*)d_in[1];   // codebook [1048576]
    float*       out = (float*)d_out;           // [1 + 16777216]
    char*        ws  = (char*)d_ws;
    float*       csq = (float*)(ws + WS_CSQ);

    hipMemsetAsync(d_out, 0, sizeof(float), stream);

    if (ws_size >= WS_NEED) {
        uint4* bch   = (uint4*)(ws + WS_BH);
        uint4* bcl   = (uint4*)(ws + WS_BL);
        int*   candw = (int*)(ws + WS_CAND);
        cvt_cb_kernel<<<NH * NK / 8, 256, 0, stream>>>(cb, bch, bcl, csq);
        dim3 grid(NTOK / 128, NH);
        vq_mfma<<<grid, 256, 0, stream>>>(x, csq, bch, bcl, candw);
        vq_tail<<<NTOK * NH / 32, 64, 0, stream>>>(x, cb, candw, out);
    } else {
        csq_kernel<<<NH * NK, 64, 0, stream>>>(cb, csq);
        dim3 grid(NTOK / TN, NH);
        vq_main_fp32<<<grid, 256, 0, stream>>>(x, cb, csq, out);
    }
}

// Round 7
// 286.601 us; speedup vs baseline: 1.6393x; 1.0755x over previous
//
#include <hip/hip_runtime.h>
#include <cfloat>

// Problem constants (fixed by the reference):
//   inputs  [8,2048,1024] fp32 -> flat [N=16384, H=4, dh=256]
//   codebook[H=4, K=1024, dh=256] fp32
//   out[0] = loss, out[1..] = quantized (16777216 floats)
#define NH    4
#define NK    1024
#define DHD   256
#define NTOK  16384
#define ROWS  (NH * DHD)   // 1024 floats per token row

typedef __attribute__((ext_vector_type(8))) short bf16x8;
typedef __attribute__((ext_vector_type(4))) float f32x4;

// ---------------------------------------------------------------------------
// Workspace layout (bytes). Fast path needs ~4.7 MB; else fp32 fallback.
// ---------------------------------------------------------------------------
#define WS_CSQ  ((size_t)0)
#define WS_BH   ((size_t)16384)                    // cb hi: 4*8*4*1024*16 = 2 MB
#define WS_BL   (WS_BH + (size_t)2097152)          // cb lo: 2 MB
#define WS_CAND (WS_BL + (size_t)2097152)          // cand pairs: 65536*2*4 = 512 KB
#define WS_NEED (WS_CAND + (size_t)524288)

// ---------------------------------------------------------------------------
// bf16 split helpers (round-to-nearest-even)
// ---------------------------------------------------------------------------
__device__ __forceinline__ unsigned short f32_to_bf16_rn(float f) {
    unsigned u = __float_as_uint(f);
    u += 0x7FFFu + ((u >> 16) & 1u);
    return (unsigned short)(u >> 16);
}
__device__ __forceinline__ float bf16_as_f32(unsigned short h) {
    return __uint_as_float(((unsigned)h) << 16);
}

// direct global->LDS DMA, 16B per lane, dest = wave-uniform base + lane*16
__device__ __forceinline__ void gload_lds16(const uint4* g, uint4* l) {
    __builtin_amdgcn_global_load_lds(
        (const __attribute__((address_space(1))) void*)g,
        (__attribute__((address_space(3))) void*)l, 16, 0, 0);
}

// ---------------------------------------------------------------------------
// Kernel 0 (FALLBACK PATH ONLY): per-code squared norms.
// Fast path computes csq inside cvt_cb_kernel.
// ---------------------------------------------------------------------------
__global__ __launch_bounds__(64) void csq_kernel(const float* __restrict__ cb,
                                                 float* __restrict__ csq) {
    const int code = blockIdx.x;                 // 0 .. NH*NK-1
    const int lane = threadIdx.x;
    const float4 v = *(const float4*)(cb + (size_t)code * DHD + lane * 4);
    float s = v.x * v.x + v.y * v.y + v.z * v.z + v.w * v.w;
#pragma unroll
    for (int off = 32; off > 0; off >>= 1) s += __shfl_down(s, off, 64);
    if (lane == 0) csq[code] = s;
}

// ---------------------------------------------------------------------------
// cvt_cb: codebook fp32 -> hi/lo bf16, swizzled [h][dc][kk][code] 16B units,
// PLUS per-code squared norms (fp32) — csq only screens; refine recomputes
// exactly, so the reduction-order difference vs csq_kernel is harmless.
// Block 256 threads = 8 codes (32 lanes per code).
// ---------------------------------------------------------------------------
__global__ __launch_bounds__(256) void cvt_cb_kernel(const float* __restrict__ cb,
                                                     uint4* __restrict__ bch,
                                                     uint4* __restrict__ bcl,
                                                     float* __restrict__ csq) {
    const int g = blockIdx.x * 8 + (threadIdx.x >> 5);   // 0..4095
    const int o = threadIdx.x & 31;                      // dh-octet
    const float* src = cb + (size_t)g * DHD + o * 8;
    unsigned wh[4], wl[4];
    float s = 0.f;
#pragma unroll
    for (int i = 0; i < 4; ++i) {
        const float f0 = src[2 * i], f1 = src[2 * i + 1];
        s += f0 * f0 + f1 * f1;
        const unsigned short h0 = f32_to_bf16_rn(f0);
        const unsigned short h1 = f32_to_bf16_rn(f1);
        const unsigned short l0 = f32_to_bf16_rn(f0 - bf16_as_f32(h0));
        const unsigned short l1 = f32_to_bf16_rn(f1 - bf16_as_f32(h1));
        wh[i] = (unsigned)h0 | ((unsigned)h1 << 16);
        wl[i] = (unsigned)l0 | ((unsigned)l1 << 16);
    }
    const int hh = g >> 10, c = g & 1023, dc = o >> 2, kk = o & 3;
    const size_t unit = (size_t)((hh * 8 + dc) * 4 + kk) * NK + c;
    bch[unit] = make_uint4(wh[0], wh[1], wh[2], wh[3]);
    bcl[unit] = make_uint4(wl[0], wl[1], wl[2], wl[3]);
    // 32-lane reduction for this code's norm
#pragma unroll
    for (int m = 16; m > 0; m >>= 1) s += __shfl_xor(s, m, 32);
    if (o == 0) csq[g] = s;
}

// first-index "less" for (value, index) pairs
__device__ __forceinline__ bool lt_vi(float v, int i, float w, int j) {
    return (v < w) || (v == w && i < j);
}

// ---------------------------------------------------------------------------
// Bit-exact replica of numpy's pairwise sum of squares for n=256 (VERIFIED R5)
// (retained for the fp32 fallback kernel)
// ---------------------------------------------------------------------------
__device__ __forceinline__ float np_sq_pairwise256(const float* __restrict__ a) {
#pragma clang fp contract(off)
    float tot = 0.f;
#pragma unroll
    for (int blk = 0; blk < 2; ++blk) {
        const float* p = a + blk * 128;
        float r0 = p[0] * p[0], r1 = p[1] * p[1], r2 = p[2] * p[2], r3 = p[3] * p[3];
        float r4 = p[4] * p[4], r5 = p[5] * p[5], r6 = p[6] * p[6], r7 = p[7] * p[7];
#pragma clang loop unroll_count(2)
        for (int i = 8; i < 128; i += 8) {
            r0 = r0 + p[i + 0] * p[i + 0];
            r1 = r1 + p[i + 1] * p[i + 1];
            r2 = r2 + p[i + 2] * p[i + 2];
            r3 = r3 + p[i + 3] * p[i + 3];
            r4 = r4 + p[i + 4] * p[i + 4];
            r5 = r5 + p[i + 5] * p[i + 5];
            r6 = r6 + p[i + 6] * p[i + 6];
            r7 = r7 + p[i + 7] * p[i + 7];
        }
        const float res = ((r0 + r1) + (r2 + r3)) + ((r4 + r5) + (r6 + r7));
        tot = (blk == 0) ? res : (tot + res);
    }
    return tot;
}

// Bit-exact replica of np.einsum's sequential fp32 mul+add loop (VERIFIED R5).
__device__ __forceinline__ float np_dot_seq256(const float* __restrict__ a,
                                               const float* __restrict__ b) {
#pragma clang fp contract(off)
    float s = 0.f;
#pragma clang loop unroll_count(4)
    for (int i = 0; i < 256; ++i) s = s + a[i] * b[i];
    return s;
}

// ---------------------------------------------------------------------------
// Single-pass exact refinement, spill-proof codegen (R5/R6 hardware-verified:
// passed, WRITE_SIZE clean in its own kernel). Partial unroll keeps ~16
// float4 loads in flight; all indices compile-time.
// Association order identical to np_sq_pairwise256 / np_dot_seq256.
// ---------------------------------------------------------------------------
__device__ __forceinline__ void refine_exact(const float* __restrict__ xr,
                                             const float* __restrict__ cr,
                                             float& Xo, float& Co, float& Do) {
#pragma clang fp contract(off)
    float s = 0.f;
    float X = 0.f, C = 0.f;
    for (int blk = 0; blk < 2; ++blk) {
        const float4* xq = (const float4*)(xr + blk * 128);
        const float4* cq = (const float4*)(cr + blk * 128);
        float xa[8], ca[8];
#pragma unroll
        for (int j = 0; j < 8; ++j) { xa[j] = 0.f; ca[j] = 0.f; }
#pragma clang loop unroll_count(4)
        for (int g = 0; g < 16; ++g) {
            const float4 a0 = xq[2 * g], a1 = xq[2 * g + 1];
            const float4 b0 = cq[2 * g], b1 = cq[2 * g + 1];
            const float xf[8] = {a0.x, a0.y, a0.z, a0.w, a1.x, a1.y, a1.z, a1.w};
            const float cf[8] = {b0.x, b0.y, b0.z, b0.w, b1.x, b1.y, b1.z, b1.w};
#pragma unroll
            for (int j = 0; j < 8; ++j) {
                xa[j] = xa[j] + xf[j] * xf[j];
                ca[j] = ca[j] + cf[j] * cf[j];
            }
#pragma unroll
            for (int j = 0; j < 8; ++j) s = s + xf[j] * cf[j];
        }
        const float xres = ((xa[0] + xa[1]) + (xa[2] + xa[3])) + ((xa[4] + xa[5]) + (xa[6] + xa[7]));
        const float cres = ((ca[0] + ca[1]) + (ca[2] + ca[3])) + ((ca[4] + ca[5]) + (ca[6] + ca[7]));
        X = (blk == 0) ? xres : (X + xres);
        C = (blk == 0) ? cres : (C + cres);
    }
    Xo = X; Co = C; Do = s;
}

// ===========================================================================
// SCREEN kernel: R6's verified body with 64-token blocks -> grid 1024
// (R6 post-mortem: 512-block grid hard-capped residency at 2 blocks/CU;
// occupancy was grid-limited, not resource-limited). Each wave owns ONE
// 16-row MFMA tile (A-frags 64 VGPR, natural allocation ~110-120 under the
// 128 tier -> 4 waves/SIMD; LDS 36.9 KB -> 4 blocks/CU = 16 waves/CU).
// NO forced min-occupancy bound (R3 lesson: forcing caused 64-VGPR spill).
// Grid (NTOK/64, NH), 256 thr / 4 waves; wave w: tokens w*16..w*16+15.
// Codes in KT=32 tiles (2 col-tiles), single-buffered — staging and math
// identical to R6's passing kernel minus the rt dimension.
// dot = hi*hi + hi*lo + lo*hi via mfma_f32_16x16x32_bf16.
// Layouts (doc-verified): A-frag A[m=lane&15][k=(lane>>4)*8+j];
// B-frag (B^T input [code][dh]): B[n=lane&15][k=(lane>>4)*8+j];
// C/D: col(n)=lane&15, row(m)=(lane>>4)*4+reg.
// ===========================================================================
#define BT 64            // tokens per block
#define KT 32            // codes per tile
#define NTIL (NK / KT)   // 32 tiles

__global__ __launch_bounds__(256, 2) void vq_mfma(const float* __restrict__ x,
                                                  const float* __restrict__ csq,
                                                  const uint4* __restrict__ bch,
                                                  const uint4* __restrict__ bcl,
                                                  int* __restrict__ candw) {
    __shared__ uint4 BsH[1024];    // 32 codes x 256 dh (hi) as [dcKK(32)][code(32)]
    __shared__ uint4 BsL[1024];    // lo
    __shared__ float Cs[NK];       // per-head code norms, loaded once

    const int tid  = threadIdx.x;
    const int h    = blockIdx.y;
    const int t0   = blockIdx.x * BT;
    const int wv   = tid >> 6;
    const int lane = tid & 63;
    const int kk   = lane >> 4;    // 0..3 (k-octet)
    const int ln   = lane & 15;

    // Code norms: whole head once.
#pragma unroll
    for (int i = tid; i < NK; i += 256) Cs[i] = csq[h * NK + i];

    // A fragments: token-stationary, whole dh in registers (hi+lo, 64 VGPR),
    // converted in-registers from fp32 x (bit-exact split).
    bf16x8 aH[8], aL[8];
    {
        const int tokb = t0 + wv * 16 + ln;
        const float* xa = x + (size_t)tokb * ROWS + h * DHD + kk * 8;
#pragma unroll
        for (int dc = 0; dc < 8; ++dc) {
            const float* p = xa + dc * 32;
            const float4 f0 = *(const float4*)p;
            const float4 f1 = *(const float4*)(p + 4);
            const float f[8] = {f0.x, f0.y, f0.z, f0.w, f1.x, f1.y, f1.z, f1.w};
            bf16x8 hv, lv;
#pragma unroll
            for (int j = 0; j < 8; ++j) {
                const unsigned short hb = f32_to_bf16_rn(f[j]);
                hv[j] = (short)hb;
                lv[j] = (short)f32_to_bf16_rn(f[j] - bf16_as_f32(hb));
            }
            aH[dc] = hv;
            aL[dc] = lv;
        }
    }

    float b1[4], b2[4];
    int   i1[4], i2[4];
#pragma unroll
    for (int s = 0; s < 4; ++s) { b1[s] = FLT_MAX; b2[s] = FLT_MAX; i1[s] = 0; i2[s] = 0; }

    for (int t = 0; t < NTIL; ++t) {
        const int k0 = t * KT;
        __syncthreads();  // protect Bs from previous-iteration readers
        // stage B tile: 1024 hi + 1024 lo units via direct global->LDS DMA.
        // Wave wv, chunk q=wv*4+p: lane l -> row 2q+(l>>5), col l&31;
        // LDS dest unit q*64+l == row*32+col (linear match, wave-uniform base).
#pragma unroll
        for (int p = 0; p < 4; ++p) {
            const int q   = wv * 4 + p;
            const int row = 2 * q + (lane >> 5);
            const size_t w = (size_t)(h * 32 + row) * NK + k0 + (lane & 31);
            gload_lds16(&bch[w], &BsH[q * 64]);
            gload_lds16(&bcl[w], &BsL[q * 64]);
        }
        __syncthreads();  // drains vmcnt(0): DMA'd tile visible

        f32x4 acc[2];
#pragma unroll
        for (int ct = 0; ct < 2; ++ct) acc[ct] = (f32x4){0.f, 0.f, 0.f, 0.f};

#pragma unroll
        for (int dc = 0; dc < 8; ++dc) {
#pragma unroll
            for (int ct = 0; ct < 2; ++ct) {
                const int bu = (dc * 4 + kk) * 32 + ct * 16 + ln;
                const bf16x8 bH = *(const bf16x8*)&BsH[bu];
                const bf16x8 bL = *(const bf16x8*)&BsL[bu];
                acc[ct] = __builtin_amdgcn_mfma_f32_16x16x32_bf16(aH[dc], bH, acc[ct], 0, 0, 0);
                acc[ct] = __builtin_amdgcn_mfma_f32_16x16x32_bf16(aH[dc], bL, acc[ct], 0, 0, 0);
                acc[ct] = __builtin_amdgcn_mfma_f32_16x16x32_bf16(aL[dc], bH, acc[ct], 0, 0, 0);
            }
        }

        // distances (x_sq dropped: per-token constant) + running top-2
#pragma unroll
        for (int ct = 0; ct < 2; ++ct) {
            const float cs   = Cs[k0 + ct * 16 + ln];
            const int   codg = k0 + ct * 16 + ln;
#pragma unroll
            for (int r = 0; r < 4; ++r) {
                const float dist = cs - 2.f * acc[ct][r];
                if (dist < b1[r]) { b2[r] = b1[r]; i2[r] = i1[r]; b1[r] = dist; i1[r] = codg; }
                else if (dist < b2[r]) { b2[r] = dist; i2[r] = codg; }
            }
        }
    }

    // Merge top-2 across the 16 lanes sharing each token (xor bits 0..3;
    // token row m = kk*4+r lives at the 16 lanes with the same kk),
    // then write candidate pairs straight to workspace.
#pragma unroll
    for (int s = 0; s < 4; ++s) {
        float v1 = b1[s], v2 = b2[s];
        int   j1 = i1[s], j2 = i2[s];
#pragma unroll
        for (int m = 1; m <= 8; m <<= 1) {
            const float o1 = __shfl_xor(v1, m, 64);
            const int   oj1 = __shfl_xor(j1, m, 64);
            const float o2 = __shfl_xor(v2, m, 64);
            const int   oj2 = __shfl_xor(j2, m, 64);
            if (lt_vi(o1, oj1, v1, j1)) {
                if (lt_vi(v1, j1, o2, oj2)) { v2 = v1; j2 = j1; }
                else                        { v2 = o2; j2 = oj2; }
                v1 = o1; j1 = oj1;
            } else if (lt_vi(o1, oj1, v2, j2)) {
                v2 = o1; j2 = oj1;
            }
        }
        if (ln == 0) {
            const int tl  = wv * 16 + kk * 4 + s;
            const int gid = h * NTOK + t0 + tl;
            candw[2 * gid + 0] = j1;
            candw[2 * gid + 1] = j2;
        }
    }
}

// ===========================================================================
// TAIL kernel: refinement + select + gather + loss, own register file.
// Loss comes from refine's exact sums: for the selected code,
// sum((q-x)^2) == X + C - 2D (algebraic identity on the exact fp32 values).
// 1 wave per block, 32 (token,head)-rows, 2 lanes per row. Grid 2048.
// ===========================================================================
__global__ __launch_bounds__(64) void vq_tail(const float* __restrict__ x,
                                              const float* __restrict__ cb,
                                              const int* __restrict__ candw,
                                              float* __restrict__ out) {
    const int lane = threadIdx.x;          // 0..63
    const int rowb = blockIdx.x * 32;      // rows = h*NTOK + t, h uniform in block
    const int h    = rowb >> 14;           // NTOK = 2^14
    const int tb   = rowb & (NTOK - 1);
    const float* cbh = cb + (size_t)h * NK * DHD;

    // Refinement: bit-exact numpy emulation on the 2 candidates.
    const int rloc = lane >> 1;            // 0..31
    const int cand = lane & 1;
    const int row  = rowb + rloc;
    const int t    = tb + rloc;
    const int code = candw[2 * row + cand];
    const float* xr = x + (size_t)t * ROWS + h * DHD;
    const float* cr = cbh + (size_t)code * DHD;
    float X, C, D;
    refine_exact(xr, cr, X, C, D);
    float d;
    {
#pragma clang fp contract(off)
        const float tt = X + C;
        d = tt - 2.0f * D;
    }
    const float od = __shfl_xor(d, 1, 64);
    int   sel  = code;                     // meaningful in cand==0 lanes
    float lacc = 0.f;
    if (cand == 0) {
        const int jB = candw[2 * row + 1];
        const bool pickB = (od < d) || (od == d && jB < code);
        sel  = pickB ? jB : code;
        lacc = pickB ? od : d;             // selected (q-x)^2 row-sum, exact
    }

    // Epilogue: per row, 64 lanes x float4 = the full 256-float slice.
    for (int r = 0; r < 32; ++r) {
        const int cr_code = __shfl(sel, 2 * r, 64);
        const int tr = tb + r;
        const float4 q4 = *(const float4*)(cbh + (size_t)cr_code * DHD + (lane << 2));
        *(float4*)(out + 1 + (size_t)tr * ROWS + h * DHD + (lane << 2)) = q4;
    }
#pragma unroll
    for (int off = 32; off > 0; off >>= 1) lacc += __shfl_down(lacc, off, 64);
    if (lane == 0) atomicAdd(out, lacc * (0.25f / 16777216.f));  // 0.25 * mean
}

// ===========================================================================
// FALLBACK (ws too small): R6 fp32 kernel — verified passing at 558 us.
// ===========================================================================
#define TN 128
#define TK 128
#define KC 16
#define APAD 4
#define BPAD 4

__global__ __launch_bounds__(256, 2) void vq_main_fp32(const float* __restrict__ x,
                                                       const float* __restrict__ cb,
                                                       const float* __restrict__ csq,
                                                       float* __restrict__ out) {
    __shared__ float As[KC][TN + APAD];
    __shared__ float Bs[KC][TK + BPAD];
    __shared__ float Cs[TK];
    __shared__ int   Cand[TN][2];
    __shared__ int   SIdx[TN];
    __shared__ float WSum[4];

    const int tid = threadIdx.x;
    const int h   = blockIdx.y;
    const int t0  = blockIdx.x * TN;
    const int ty  = tid >> 4;
    const int tx  = tid & 15;

    const float* xh  = x  + (size_t)t0 * ROWS + h * DHD;
    const float* cbh = cb + (size_t)h * NK * DHD;

    const int sr = tid >> 1;
    const int sd = (tid & 1) << 3;

    float b1[8], b2[8];
    int   i1[8], i2[8];
#pragma unroll
    for (int r = 0; r < 8; ++r) { b1[r] = FLT_MAX; b2[r] = FLT_MAX; i1[r] = 0; i2[r] = 0; }

    for (int k0 = 0; k0 < NK; k0 += TK) {
        __syncthreads();
        if (tid < TK) Cs[tid] = csq[h * NK + k0 + tid];

        float acc[8][8];
#pragma unroll
        for (int r = 0; r < 8; ++r)
#pragma unroll
            for (int c = 0; c < 8; ++c) acc[r][c] = 0.f;

        for (int d0 = 0; d0 < DHD; d0 += KC) {
            __syncthreads();
            {
                const float* ap = xh + (size_t)sr * ROWS + d0 + sd;
                const float4 a0 = *(const float4*)ap;
                const float4 a1 = *(const float4*)(ap + 4);
                As[sd + 0][sr] = a0.x; As[sd + 1][sr] = a0.y;
                As[sd + 2][sr] = a0.z; As[sd + 3][sr] = a0.w;
                As[sd + 4][sr] = a1.x; As[sd + 5][sr] = a1.y;
                As[sd + 6][sr] = a1.z; As[sd + 7][sr] = a1.w;
            }
            {
                const float* bp = cbh + (size_t)(k0 + sr) * DHD + d0 + sd;
                const float4 b0v = *(const float4*)bp;
                const float4 b1v = *(const float4*)(bp + 4);
                Bs[sd + 0][sr] = b0v.x; Bs[sd + 1][sr] = b0v.y;
                Bs[sd + 2][sr] = b0v.z; Bs[sd + 3][sr] = b0v.w;
                Bs[sd + 4][sr] = b1v.x; Bs[sd + 5][sr] = b1v.y;
                Bs[sd + 6][sr] = b1v.z; Bs[sd + 7][sr] = b1v.w;
            }
            __syncthreads();
#pragma unroll 4
            for (int kc = 0; kc < KC; ++kc) {
                const float4 a0 = *(const float4*)&As[kc][ty << 3];
                const float4 a1 = *(const float4*)&As[kc][(ty << 3) + 4];
                const float4 p0 = *(const float4*)&Bs[kc][tx << 2];
                const float4 p1 = *(const float4*)&Bs[kc][64 + (tx << 2)];
                const float aa[8] = {a0.x, a0.y, a0.z, a0.w, a1.x, a1.y, a1.z, a1.w};
                const float bb[8] = {p0.x, p0.y, p0.z, p0.w, p1.x, p1.y, p1.z, p1.w};
#pragma unroll
                for (int r = 0; r < 8; ++r)
#pragma unroll
                    for (int c = 0; c < 8; ++c)
                        acc[r][c] = fmaf(aa[r], bb[c], acc[r][c]);
            }
        }
#pragma unroll
        for (int r = 0; r < 8; ++r) {
#pragma unroll
            for (int c = 0; c < 8; ++c) {
                const int cc = (c < 4) ? ((tx << 2) + c) : (64 + (tx << 2) + c - 4);
                const float dist = Cs[cc] - 2.f * acc[r][c];
                const int   idx  = k0 + cc;
                if (dist < b1[r]) { b2[r] = b1[r]; i2[r] = i1[r]; b1[r] = dist; i1[r] = idx; }
                else if (dist < b2[r]) { b2[r] = dist; i2[r] = idx; }
            }
        }
    }

#pragma unroll
    for (int r = 0; r < 8; ++r) {
        float v1 = b1[r], v2 = b2[r];
        int   j1 = i1[r], j2 = i2[r];
#pragma unroll
        for (int m = 1; m <= 8; m <<= 1) {
            const float o1 = __shfl_xor(v1, m, 64);
            const int   oj1 = __shfl_xor(j1, m, 64);
            const float o2 = __shfl_xor(v2, m, 64);
            const int   oj2 = __shfl_xor(j2, m, 64);
            if (lt_vi(o1, oj1, v1, j1)) {
                if (lt_vi(v1, j1, o2, oj2)) { v2 = v1; j2 = j1; }
                else                        { v2 = o2; j2 = oj2; }
                v1 = o1; j1 = oj1;
            } else if (lt_vi(o1, oj1, v2, j2)) {
                v2 = o1; j2 = oj1;
            }
        }
        b1[r] = v1; i1[r] = j1; b2[r] = v2; i2[r] = j2;
    }
    if (tx == 0) {
#pragma unroll
        for (int r = 0; r < 8; ++r) {
            Cand[(ty << 3) + r][0] = i1[r];
            Cand[(ty << 3) + r][1] = i2[r];
        }
    }
    __syncthreads();

    {
        const int token = tid >> 1;
        const int cand  = tid & 1;
        const int code  = Cand[token][cand];
        const float* xr = xh + (size_t)token * ROWS;
        const float* cr = cbh + (size_t)code * DHD;
        const float X = np_sq_pairwise256(xr);
        const float C = np_sq_pairwise256(cr);
        const float D = np_dot_seq256(xr, cr);
        float d;
        {
#pragma clang fp contract(off)
            const float t = X + C;
            d = t - 2.0f * D;
        }
        const float od = __shfl_xor(d, 1, 64);
        if (cand == 0) {
            const int jA = code;
            const int jB = Cand[token][1];
            const bool pickB = (od < d) || (od == d && jB < jA);
            SIdx[token] = pickB ? jB : jA;
        }
    }
    __syncthreads();

    const int wav  = tid >> 6;
    const int lane = tid & 63;
    float lacc = 0.f;
    for (int t = wav; t < TN; t += 4) {
        const float4 q4 = *(const float4*)(cbh + (size_t)SIdx[t] * DHD + (lane << 2));
        const float4 x4 = *(const float4*)(xh + (size_t)t * ROWS + (lane << 2));
        const float dx = q4.x - x4.x, dy = q4.y - x4.y;
        const float dz = q4.z - x4.z, dw = q4.w - x4.w;
        lacc += dx * dx + dy * dy + dz * dz + dw * dw;
        *(float4*)(out + 1 + (size_t)(t0 + t) * ROWS + h * DHD + (lane << 2)) = q4;
    }
#pragma unroll
    for (int off = 32; off > 0; off >>= 1) lacc += __shfl_down(lacc, off, 64);
    if (lane == 0) WSum[wav] = lacc;
    __syncthreads();
    if (tid == 0) {
        const float s = WSum[0] + WSum[1] + WSum[2] + WSum[3];
        atomicAdd(out, s * (0.25f / 16777216.f));
    }
}

extern "C" void kernel_launch(void* const* d_in, const int* in_sizes, int n_in,
                              void* d_out, int out_size, void* d_ws, size_t ws_size,
                              hipStream_t stream) {
    const float* x   = (const float*)d_in[0];   // inputs  [16777216]
    const float* cb  = (const float*)d_in[1];   // codebook [1048576]
    float*       out = (float*)d_out;           // [1 + 16777216]
    char*        ws  = (char*)d_ws;
    float*       csq = (float*)(ws + WS_CSQ);

    hipMemsetAsync(d_out, 0, sizeof(float), stream);

    if (ws_size >= WS_NEED) {
        uint4* bch   = (uint4*)(ws + WS_BH);
        uint4* bcl   = (uint4*)(ws + WS_BL);
        int*   candw = (int*)(ws + WS_CAND);
        cvt_cb_kernel<<<NH * NK / 8, 256, 0, stream>>>(cb, bch, bcl, csq);
        dim3 grid(NTOK / BT, NH);
        vq_mfma<<<grid, 256, 0, stream>>>(x, csq, bch, bcl, candw);
        vq_tail<<<NTOK * NH / 32, 64, 0, stream>>>(x, cb, candw, out);
    } else {
        csq_kernel<<<NH * NK, 64, 0, stream>>>(cb, csq);
        dim3 grid(NTOK / TN, NH);
        vq_main_fp32<<<grid, 256, 0, stream>>>(x, cb, csq, out);
    }
}